// Round 2
// baseline (2331.513 us; speedup 1.0000x reference)
//
#include <hip/hip_runtime.h>
#include <hip/hip_bf16.h>
#include <math.h>

// Problem constants (MambaEncoder)
#define Bz     8
#define Lz     8192
#define DM     128      // d_model
#define DI     256      // d_inner
#define DS     16       // d_state
#define DTR    8        // dt_rank
#define NDBL   40       // DTR + 2*DS
#define DEPTHN 4
#define BLz    (Bz*Lz)  // 65536 tokens
#define CHT    128      // scan chunk length
#define NCH    (Lz/CHT) // 64 chunks per sequence

typedef unsigned short bf16_t;

__device__ __forceinline__ float bf2f(bf16_t u) {
    return __uint_as_float(((unsigned)u) << 16);
}
__device__ __forceinline__ bf16_t f2bf(float f) {
    unsigned u = __float_as_uint(f);
    u = u + 0x7FFFu + ((u >> 16) & 1u);   // round-to-nearest-even
    return (bf16_t)(u >> 16);
}

// ---------------------------------------------------------------------------
// Zero h_global accumulator (graph-capture-safe; no hipMemsetAsync).
// ---------------------------------------------------------------------------
__global__ void k_zero_hg(float* __restrict__ hg) {
    int i = blockIdx.x * 256 + threadIdx.x;
    if (i < Bz * DM) hg[i] = 0.f;
}

// ---------------------------------------------------------------------------
// Input projection: h[b,l,d] = proj_b[d] + sum_c x[b,c,l]*proj_w[d,c]
// ---------------------------------------------------------------------------
__global__ __launch_bounds__(256) void k_inproj(const float* __restrict__ x,
                                                const float* __restrict__ pw,
                                                const float* __restrict__ pb,
                                                float* __restrict__ h) {
    int t = blockIdx.x * 2 + (threadIdx.x >> 7);
    int d = threadIdx.x & 127;
    int b = t >> 13, l = t & (Lz - 1);
    float acc = pb[d];
#pragma unroll
    for (int c = 0; c < 3; ++c)
        acc += x[(size_t)(b * 3 + c) * Lz + l] * pw[d * 3 + c];
    h[(size_t)t * DM + d] = acc;
}

// ---------------------------------------------------------------------------
// LayerNorm over d_model=128 -> bf16 output. 16 lanes/token, 16 tokens/block.
// ---------------------------------------------------------------------------
__global__ __launch_bounds__(256) void k_ln(const float* __restrict__ h,
                                            const float* __restrict__ w,
                                            const float* __restrict__ bias,
                                            bf16_t* __restrict__ xn) {
    int t    = blockIdx.x * 16 + (threadIdx.x >> 4);
    int lane = threadIdx.x & 15;
    const float4* hp = (const float4*)(h + (size_t)t * DM + lane * 8);
    float4 v0 = hp[0], v1 = hp[1];
    float s = v0.x + v0.y + v0.z + v0.w + v1.x + v1.y + v1.z + v1.w;
    float q = v0.x*v0.x + v0.y*v0.y + v0.z*v0.z + v0.w*v0.w +
              v1.x*v1.x + v1.y*v1.y + v1.z*v1.z + v1.w*v1.w;
#pragma unroll
    for (int off = 1; off < 16; off <<= 1) {
        s += __shfl_xor(s, off);
        q += __shfl_xor(q, off);
    }
    float mean = s * (1.f / DM);
    float var  = q * (1.f / DM) - mean * mean;
    float rstd = rsqrtf(var + 1e-5f);
    const float4* wp = (const float4*)(w + lane * 8);
    const float4* bp = (const float4*)(bias + lane * 8);
    float4 w0 = wp[0], w1 = wp[1], b0 = bp[0], b1 = bp[1];
    ushort4 o0, o1;
    o0.x = f2bf((v0.x - mean) * rstd * w0.x + b0.x);
    o0.y = f2bf((v0.y - mean) * rstd * w0.y + b0.y);
    o0.z = f2bf((v0.z - mean) * rstd * w0.z + b0.z);
    o0.w = f2bf((v0.w - mean) * rstd * w0.w + b0.w);
    o1.x = f2bf((v1.x - mean) * rstd * w1.x + b1.x);
    o1.y = f2bf((v1.y - mean) * rstd * w1.y + b1.y);
    o1.z = f2bf((v1.z - mean) * rstd * w1.z + b1.z);
    o1.w = f2bf((v1.w - mean) * rstd * w1.w + b1.w);
    ushort4* op = (ushort4*)(xn + (size_t)t * DM + lane * 8);
    op[0] = o0; op[1] = o1;
}

// ---------------------------------------------------------------------------
// GEMM tile: C[64x64] = A_bf16[64xK] * W_f32[NxK]^T, K-chunks of 64.
// LDS transposed [k][m], pad 68 keeps 16B alignment for float4 reads.
// 256 threads, per-thread 4x4 register tile, fp32 accumulate.
// ---------------------------------------------------------------------------
#define GPAD 68

template <int KTOT, int NVALID>
__device__ __forceinline__ void gemm_tile(const bf16_t* __restrict__ A,
                                          const float* __restrict__ W,
                                          int mBase, int nBase,
                                          float* As, float* Ws,
                                          float acc[4][4]) {
    const int tid = threadIdx.x;
    const int tm = tid >> 4, tn = tid & 15;
    for (int kc = 0; kc < KTOT; kc += 64) {
        for (int i = tid; i < 1024; i += 256) {
            int m = i >> 4, k4 = i & 15;
            ushort4 uv = *(const ushort4*)&A[(size_t)(mBase + m) * KTOT + kc + k4 * 4];
            As[(k4 * 4 + 0) * GPAD + m] = bf2f(uv.x);
            As[(k4 * 4 + 1) * GPAD + m] = bf2f(uv.y);
            As[(k4 * 4 + 2) * GPAD + m] = bf2f(uv.z);
            As[(k4 * 4 + 3) * GPAD + m] = bf2f(uv.w);
        }
        for (int i = tid; i < 1024; i += 256) {
            int n = i >> 4, k4 = i & 15;
            float4 v = make_float4(0.f, 0.f, 0.f, 0.f);
            if (nBase + n < NVALID)
                v = *(const float4*)&W[(size_t)(nBase + n) * KTOT + kc + k4 * 4];
            Ws[(k4 * 4 + 0) * GPAD + n] = v.x;
            Ws[(k4 * 4 + 1) * GPAD + n] = v.y;
            Ws[(k4 * 4 + 2) * GPAD + n] = v.z;
            Ws[(k4 * 4 + 3) * GPAD + n] = v.w;
        }
        __syncthreads();
#pragma unroll 8
        for (int k = 0; k < 64; ++k) {
            float4 a = *(const float4*)&As[k * GPAD + tm * 4];
            float4 b = *(const float4*)&Ws[k * GPAD + tn * 4];
            acc[0][0] += a.x * b.x; acc[0][1] += a.x * b.y; acc[0][2] += a.x * b.z; acc[0][3] += a.x * b.w;
            acc[1][0] += a.y * b.x; acc[1][1] += a.y * b.y; acc[1][2] += a.y * b.z; acc[1][3] += a.y * b.w;
            acc[2][0] += a.z * b.x; acc[2][1] += a.z * b.y; acc[2][2] += a.z * b.z; acc[2][3] += a.z * b.w;
            acc[3][0] += a.w * b.x; acc[3][1] += a.w * b.y; acc[3][2] += a.w * b.z; acc[3][3] += a.w * b.w;
        }
        __syncthreads();
    }
}

// xz = xn @ in_w^T ; split into u_pre (n<256) and z (n>=256), bf16 outputs.
__global__ __launch_bounds__(256) void k_gemm_in(const bf16_t* __restrict__ xn,
                                                 const float* __restrict__ inw,
                                                 bf16_t* __restrict__ u_pre,
                                                 bf16_t* __restrict__ z) {
    __shared__ float As[64 * GPAD], Ws[64 * GPAD];
    float acc[4][4] = {};
    int mBase = blockIdx.x * 64, nBase = blockIdx.y * 64;
    gemm_tile<DM, 512>(xn, inw, mBase, nBase, As, Ws, acc);
    int tm = threadIdx.x >> 4, tn = threadIdx.x & 15;
#pragma unroll
    for (int mi = 0; mi < 4; ++mi) {
        int m  = mBase + tm * 4 + mi;
        int ng = nBase + tn * 4;
        ushort4 v;
        v.x = f2bf(acc[mi][0]); v.y = f2bf(acc[mi][1]);
        v.z = f2bf(acc[mi][2]); v.w = f2bf(acc[mi][3]);
        if (ng < DI) *(ushort4*)&u_pre[(size_t)m * DI + ng] = v;
        else         *(ushort4*)&z[(size_t)m * DI + (ng - DI)] = v;
    }
}

// dbl = u @ xproj_w^T   (N=40 valid of 64), fp32 output.
__global__ __launch_bounds__(256) void k_gemm_xproj(const bf16_t* __restrict__ u,
                                                    const float* __restrict__ xw,
                                                    float* __restrict__ dbl) {
    __shared__ float As[64 * GPAD], Ws[64 * GPAD];
    float acc[4][4] = {};
    int mBase = blockIdx.x * 64;
    gemm_tile<DI, NDBL>(u, xw, mBase, 0, As, Ws, acc);
    int tm = threadIdx.x >> 4, tn = threadIdx.x & 15;
#pragma unroll
    for (int mi = 0; mi < 4; ++mi) {
        int m  = mBase + tm * 4 + mi;
        int ng = tn * 4;
        if (ng < NDBL) {
            float4 v = make_float4(acc[mi][0], acc[mi][1], acc[mi][2], acc[mi][3]);
            *(float4*)&dbl[(size_t)m * NDBL + ng] = v;
        }
    }
}

// h += yg @ out_w^T  (residual add into fp32 h)
__global__ __launch_bounds__(256) void k_gemm_out(const bf16_t* __restrict__ yg,
                                                  const float* __restrict__ ow,
                                                  float* __restrict__ h) {
    __shared__ float As[64 * GPAD], Ws[64 * GPAD];
    float acc[4][4] = {};
    int mBase = blockIdx.x * 64, nBase = blockIdx.y * 64;
    gemm_tile<DI, DM>(yg, ow, mBase, nBase, As, Ws, acc);
    int tm = threadIdx.x >> 4, tn = threadIdx.x & 15;
#pragma unroll
    for (int mi = 0; mi < 4; ++mi) {
        int m  = mBase + tm * 4 + mi;
        int ng = nBase + tn * 4;
        float4 old = *(const float4*)&h[(size_t)m * DM + ng];
        old.x += acc[mi][0]; old.y += acc[mi][1]; old.z += acc[mi][2]; old.w += acc[mi][3];
        *(float4*)&h[(size_t)m * DM + ng] = old;
    }
}

// ---------------------------------------------------------------------------
// Causal depthwise conv (k=4) + SiLU. bf16 in/out. One thread per d.
// ---------------------------------------------------------------------------
__global__ __launch_bounds__(256) void k_conv(const bf16_t* __restrict__ u_pre,
                                              const float* __restrict__ cw,
                                              const float* __restrict__ cb,
                                              bf16_t* __restrict__ u) {
    int b = blockIdx.y, c0 = blockIdx.x * 64;
    int d = threadIdx.x;
    float w0 = cw[d * 4 + 0], w1 = cw[d * 4 + 1], w2 = cw[d * 4 + 2], w3 = cw[d * 4 + 3];
    float bb = cb[d];
    size_t base = ((size_t)b * Lz) * DI + d;
    float x3 = (c0 >= 3) ? bf2f(u_pre[base + (size_t)(c0 - 3) * DI]) : 0.f;
    float x2 = (c0 >= 2) ? bf2f(u_pre[base + (size_t)(c0 - 2) * DI]) : 0.f;
    float x1 = (c0 >= 1) ? bf2f(u_pre[base + (size_t)(c0 - 1) * DI]) : 0.f;
    for (int t = 0; t < 64; ++t) {
        float x0 = bf2f(u_pre[base + (size_t)(c0 + t) * DI]);
        float conv = bb + w0 * x3 + w1 * x2 + w2 * x1 + w3 * x0;
        float sil = conv / (1.f + __expf(-conv));
        u[base + (size_t)(c0 + t) * DI] = f2bf(sil);
        x3 = x2; x2 = x1; x1 = x0;
    }
}

// ---------------------------------------------------------------------------
// Chunked parallel scan. dt/B/C recomputed from the dbl tile in LDS
// (broadcast reads, conflict-free). Phase 1: per-chunk (P=prod dA, Q=local h).
// ---------------------------------------------------------------------------
__global__ __launch_bounds__(256) void k_scan1(const float* __restrict__ dbl,
                                               const bf16_t* __restrict__ u,
                                               const float* __restrict__ dtw,
                                               const float* __restrict__ dtb,
                                               const float* __restrict__ Alog,
                                               float* __restrict__ P,
                                               float* __restrict__ Q) {
    __shared__ float Ds[CHT * NDBL];      // 20 KB
    int c = blockIdx.x, b = blockIdx.y;
    int d = threadIdx.x;
    size_t tokBase = (size_t)b * Lz + (size_t)c * CHT;
    for (int i = threadIdx.x; i < CHT * NDBL; i += 256)
        Ds[i] = dbl[tokBase * NDBL + i];
    __syncthreads();
    float w[DTR];
#pragma unroll
    for (int r = 0; r < DTR; ++r) w[r] = dtw[d * DTR + r];
    float bb = dtb[d];
    float a[DS], p[DS], q[DS];
#pragma unroll
    for (int s = 0; s < DS; ++s) {
        a[s] = -__expf(Alog[d * DS + s]);
        p[s] = 1.f; q[s] = 0.f;
    }
    const bf16_t* up = u + tokBase * DI + d;
    for (int t = 0; t < CHT; ++t) {
        float xv = bb;
#pragma unroll
        for (int r = 0; r < DTR; ++r) xv += Ds[t * NDBL + r] * w[r];
        float dtv = (xv > 20.f) ? xv : log1pf(__expf(xv));
        float uv  = bf2f(up[(size_t)t * DI]);
        float dtu = dtv * uv;
#pragma unroll
        for (int s = 0; s < DS; ++s) {
            float dA = __expf(dtv * a[s]);
            p[s] *= dA;
            q[s] = q[s] * dA + dtu * Ds[t * NDBL + DTR + s];
        }
    }
    size_t o = ((size_t)(b * NCH + c) * DI + d) * DS;
#pragma unroll
    for (int s = 0; s < DS; s += 4) {
        *(float4*)&P[o + s] = make_float4(p[s], p[s+1], p[s+2], p[s+3]);
        *(float4*)&Q[o + s] = make_float4(q[s], q[s+1], q[s+2], q[s+3]);
    }
}

// Phase 2: scan chunk summaries; P[c] overwritten in place with entry state.
__global__ __launch_bounds__(256) void k_scan2(float* __restrict__ P,
                                               const float* __restrict__ Q) {
    int gid = blockIdx.x * 256 + threadIdx.x;
    int b = gid >> 12, r = gid & 4095;            // DI*DS = 4096
    const size_t stride = (size_t)DI * DS;
    size_t base = (size_t)b * NCH * stride + r;
    float hh = 0.f;
    for (int c = 0; c < NCH; ++c) {
        size_t o = base + (size_t)c * stride;
        float p = P[o], q = Q[o];
        P[o] = hh;                                 // entry state for chunk c
        hh = p * hh + q;
    }
}

// Phase 3: replay with entry state; fuse y = (scan + u*Dp)*silu(z) -> bf16 yg.
__global__ __launch_bounds__(256) void k_scan3(const float* __restrict__ dbl,
                                               const bf16_t* __restrict__ u,
                                               const bf16_t* __restrict__ z,
                                               const float* __restrict__ dtw,
                                               const float* __restrict__ dtb,
                                               const float* __restrict__ Alog,
                                               const float* __restrict__ Dpv,
                                               const float* __restrict__ H0,
                                               bf16_t* __restrict__ yg) {
    __shared__ float Ds[CHT * NDBL];
    int c = blockIdx.x, b = blockIdx.y;
    int d = threadIdx.x;
    size_t tokBase = (size_t)b * Lz + (size_t)c * CHT;
    for (int i = threadIdx.x; i < CHT * NDBL; i += 256)
        Ds[i] = dbl[tokBase * NDBL + i];
    __syncthreads();
    float w[DTR];
#pragma unroll
    for (int r = 0; r < DTR; ++r) w[r] = dtw[d * DTR + r];
    float bb = dtb[d];
    float a[DS], hh[DS];
    size_t ho = ((size_t)(b * NCH + c) * DI + d) * DS;
#pragma unroll
    for (int s = 0; s < DS; ++s) {
        a[s]  = -__expf(Alog[d * DS + s]);
        hh[s] = H0[ho + s];
    }
    float dp = Dpv[d];
    const bf16_t* up = u + tokBase * DI + d;
    const bf16_t* zp = z + tokBase * DI + d;
    bf16_t* yp = yg + tokBase * DI + d;
    for (int t = 0; t < CHT; ++t) {
        float xv = bb;
#pragma unroll
        for (int r = 0; r < DTR; ++r) xv += Ds[t * NDBL + r] * w[r];
        float dtv = (xv > 20.f) ? xv : log1pf(__expf(xv));
        float uv  = bf2f(up[(size_t)t * DI]);
        float zv  = bf2f(zp[(size_t)t * DI]);
        float dtu = dtv * uv;
        float y = 0.f;
#pragma unroll
        for (int s = 0; s < DS; ++s) {
            float dA = __expf(dtv * a[s]);
            hh[s] = hh[s] * dA + dtu * Ds[t * NDBL + DTR + s];
            y += hh[s] * Ds[t * NDBL + DTR + DS + s];
        }
        float sil = zv / (1.f + __expf(-zv));
        yp[(size_t)t * DI] = f2bf((y + uv * dp) * sil);
    }
}

// ---------------------------------------------------------------------------
// Final LN (in place on d_out h region) + mean over L into h_global.
// ---------------------------------------------------------------------------
__global__ __launch_bounds__(256) void k_final(float* __restrict__ h,
                                               const float* __restrict__ w,
                                               const float* __restrict__ bias,
                                               float* __restrict__ hg) {
    __shared__ float sbuf[DM];
    int t    = blockIdx.x * 16 + (threadIdx.x >> 4);
    int lane = threadIdx.x & 15;
    int b    = t >> 13;
    if (threadIdx.x < DM) sbuf[threadIdx.x] = 0.f;
    __syncthreads();
    float4* hp = (float4*)(h + (size_t)t * DM + lane * 8);
    float4 v0 = hp[0], v1 = hp[1];
    float s = v0.x + v0.y + v0.z + v0.w + v1.x + v1.y + v1.z + v1.w;
    float q = v0.x*v0.x + v0.y*v0.y + v0.z*v0.z + v0.w*v0.w +
              v1.x*v1.x + v1.y*v1.y + v1.z*v1.z + v1.w*v1.w;
#pragma unroll
    for (int off = 1; off < 16; off <<= 1) {
        s += __shfl_xor(s, off);
        q += __shfl_xor(q, off);
    }
    float mean = s * (1.f / DM);
    float var  = q * (1.f / DM) - mean * mean;
    float rstd = rsqrtf(var + 1e-5f);
    const float4* wp = (const float4*)(w + lane * 8);
    const float4* bp = (const float4*)(bias + lane * 8);
    float4 w0 = wp[0], w1 = wp[1], b0 = bp[0], b1 = bp[1];
    float4 o0, o1;
    o0.x = (v0.x - mean) * rstd * w0.x + b0.x;
    o0.y = (v0.y - mean) * rstd * w0.y + b0.y;
    o0.z = (v0.z - mean) * rstd * w0.z + b0.z;
    o0.w = (v0.w - mean) * rstd * w0.w + b0.w;
    o1.x = (v1.x - mean) * rstd * w1.x + b1.x;
    o1.y = (v1.y - mean) * rstd * w1.y + b1.y;
    o1.z = (v1.z - mean) * rstd * w1.z + b1.z;
    o1.w = (v1.w - mean) * rstd * w1.w + b1.w;
    hp[0] = o0; hp[1] = o1;
    int dbase = lane * 8;
    atomicAdd(&sbuf[dbase + 0], o0.x); atomicAdd(&sbuf[dbase + 1], o0.y);
    atomicAdd(&sbuf[dbase + 2], o0.z); atomicAdd(&sbuf[dbase + 3], o0.w);
    atomicAdd(&sbuf[dbase + 4], o1.x); atomicAdd(&sbuf[dbase + 5], o1.y);
    atomicAdd(&sbuf[dbase + 6], o1.z); atomicAdd(&sbuf[dbase + 7], o1.w);
    __syncthreads();
    if (threadIdx.x < DM)
        atomicAdd(&hg[b * DM + threadIdx.x], sbuf[threadIdx.x] * (1.f / Lz));
}

// ---------------------------------------------------------------------------
extern "C" void kernel_launch(void* const* d_in, const int* in_sizes, int n_in,
                              void* d_out, int out_size, void* d_ws, size_t ws_size,
                              hipStream_t stream) {
    const float* x       = (const float*)d_in[0];
    const float* proj_w  = (const float*)d_in[1];
    const float* proj_b  = (const float*)d_in[2];
    const float* ln_w    = (const float*)d_in[3];
    const float* ln_b    = (const float*)d_in[4];
    const float* in_w    = (const float*)d_in[5];
    const float* conv_w  = (const float*)d_in[6];
    const float* conv_b  = (const float*)d_in[7];
    const float* xproj_w = (const float*)d_in[8];
    const float* dt_w    = (const float*)d_in[9];
    const float* dt_b    = (const float*)d_in[10];
    const float* A_log   = (const float*)d_in[11];
    const float* Dp      = (const float*)d_in[12];
    const float* out_w   = (const float*)d_in[13];
    const float* lnout_w = (const float*)d_in[14];
    const float* lnout_b = (const float*)d_in[15];

    float* out = (float*)d_out;
    float* h   = out;                        // [BL][128] lives in d_out
    float* hg  = out + (size_t)BLz * DM;     // [B][128]

    // Workspace layout (byte offsets; total ~138 MiB)
    char* ws = (char*)d_ws;
    bf16_t* xn    = (bf16_t*)(ws);                                   // BL*128*2 = 16 MiB
    bf16_t* u_pre = (bf16_t*)(ws + (size_t)16777216);                // BL*256*2 = 32 MiB
    bf16_t* z     = (bf16_t*)(ws + (size_t)16777216 + 33554432);     // 32 MiB
    bf16_t* u     = (bf16_t*)(ws + (size_t)16777216 + 2*33554432ULL);// 32 MiB
    float*  dbl   = (float*) (ws + (size_t)16777216 + 3*33554432ULL);// BL*40*4 = 10 MiB
    float*  P     = (float*) (ws + (size_t)16777216 + 3*33554432ULL + 10485760); // 8 MiB
    float*  Q     = (float*) (ws + (size_t)16777216 + 3*33554432ULL + 10485760 + 8388608); // 8 MiB
    bf16_t* yg    = u_pre;                   // u_pre dead after k_conv

    k_zero_hg<<<4, 256, 0, stream>>>(hg);
    k_inproj<<<BLz / 2, 256, 0, stream>>>(x, proj_w, proj_b, h);

    for (int i = 0; i < DEPTHN; ++i) {
        k_ln<<<BLz / 16, 256, 0, stream>>>(h, ln_w + i * DM, ln_b + i * DM, xn);
        k_gemm_in<<<dim3(BLz / 64, 8), 256, 0, stream>>>(
            xn, in_w + (size_t)i * 2 * DI * DM, u_pre, z);
        k_conv<<<dim3(Lz / 64, Bz), 256, 0, stream>>>(
            u_pre, conv_w + i * DI * 4, conv_b + i * DI, u);
        k_gemm_xproj<<<dim3(BLz / 64, 1), 256, 0, stream>>>(
            u, xproj_w + (size_t)i * NDBL * DI, dbl);
        k_scan1<<<dim3(NCH, Bz), 256, 0, stream>>>(
            dbl, u, dt_w + i * DI * DTR, dt_b + i * DI, A_log + i * DI * DS, P, Q);
        k_scan2<<<(Bz * DI * DS) / 256, 256, 0, stream>>>(P, Q);
        k_scan3<<<dim3(NCH, Bz), 256, 0, stream>>>(
            dbl, u, z, dt_w + i * DI * DTR, dt_b + i * DI,
            A_log + i * DI * DS, Dp + i * DI, P, yg);
        k_gemm_out<<<dim3(BLz / 64, 2), 256, 0, stream>>>(
            yg, out_w + (size_t)i * DM * DI, h);
    }

    k_final<<<BLz / 16, 256, 0, stream>>>(h, lnout_w, lnout_b, hg);
}

// Round 3
// 1668.713 us; speedup vs baseline: 1.3972x; 1.3972x over previous
//
#include <hip/hip_runtime.h>
#include <hip/hip_bf16.h>
#include <math.h>

// Problem constants (MambaEncoder)
#define Bz     8
#define Lz     8192
#define DM     128      // d_model
#define DI     256      // d_inner
#define DS     16       // d_state
#define DTR    8        // dt_rank
#define NDBL   40       // DTR + 2*DS
#define DEPTHN 4
#define BLz    (Bz*Lz)  // 65536 tokens
#define CHT    64       // scan chunk length
#define NCH    (Lz/CHT) // 128 chunks per sequence

typedef unsigned short bf16_t;

__device__ __forceinline__ float bf2f(bf16_t u) {
    return __uint_as_float(((unsigned)u) << 16);
}
__device__ __forceinline__ bf16_t f2bf(float f) {
    unsigned u = __float_as_uint(f);
    u = u + 0x7FFFu + ((u >> 16) & 1u);   // round-to-nearest-even
    return (bf16_t)(u >> 16);
}
__device__ __forceinline__ float fast_rcp(float x) {
    return __builtin_amdgcn_rcpf(x);
}

// ---------------------------------------------------------------------------
__global__ void k_zero_hg(float* __restrict__ hg) {
    int i = blockIdx.x * 256 + threadIdx.x;
    if (i < Bz * DM) hg[i] = 0.f;
}

// ---------------------------------------------------------------------------
__global__ __launch_bounds__(256) void k_inproj(const float* __restrict__ x,
                                                const float* __restrict__ pw,
                                                const float* __restrict__ pb,
                                                float* __restrict__ h) {
    int t = blockIdx.x * 2 + (threadIdx.x >> 7);
    int d = threadIdx.x & 127;
    int b = t >> 13, l = t & (Lz - 1);
    float acc = pb[d];
#pragma unroll
    for (int c = 0; c < 3; ++c)
        acc += x[(size_t)(b * 3 + c) * Lz + l] * pw[d * 3 + c];
    h[(size_t)t * DM + d] = acc;
}

// ---------------------------------------------------------------------------
__global__ __launch_bounds__(256) void k_ln(const float* __restrict__ h,
                                            const float* __restrict__ w,
                                            const float* __restrict__ bias,
                                            bf16_t* __restrict__ xn) {
    int t    = blockIdx.x * 16 + (threadIdx.x >> 4);
    int lane = threadIdx.x & 15;
    const float4* hp = (const float4*)(h + (size_t)t * DM + lane * 8);
    float4 v0 = hp[0], v1 = hp[1];
    float s = v0.x + v0.y + v0.z + v0.w + v1.x + v1.y + v1.z + v1.w;
    float q = v0.x*v0.x + v0.y*v0.y + v0.z*v0.z + v0.w*v0.w +
              v1.x*v1.x + v1.y*v1.y + v1.z*v1.z + v1.w*v1.w;
#pragma unroll
    for (int off = 1; off < 16; off <<= 1) {
        s += __shfl_xor(s, off);
        q += __shfl_xor(q, off);
    }
    float mean = s * (1.f / DM);
    float var  = q * (1.f / DM) - mean * mean;
    float rstd = rsqrtf(var + 1e-5f);
    const float4* wp = (const float4*)(w + lane * 8);
    const float4* bp = (const float4*)(bias + lane * 8);
    float4 w0 = wp[0], w1 = wp[1], b0 = bp[0], b1 = bp[1];
    ushort4 o0, o1;
    o0.x = f2bf((v0.x - mean) * rstd * w0.x + b0.x);
    o0.y = f2bf((v0.y - mean) * rstd * w0.y + b0.y);
    o0.z = f2bf((v0.z - mean) * rstd * w0.z + b0.z);
    o0.w = f2bf((v0.w - mean) * rstd * w0.w + b0.w);
    o1.x = f2bf((v1.x - mean) * rstd * w1.x + b1.x);
    o1.y = f2bf((v1.y - mean) * rstd * w1.y + b1.y);
    o1.z = f2bf((v1.z - mean) * rstd * w1.z + b1.z);
    o1.w = f2bf((v1.w - mean) * rstd * w1.w + b1.w);
    ushort4* op = (ushort4*)(xn + (size_t)t * DM + lane * 8);
    op[0] = o0; op[1] = o1;
}

// ---------------------------------------------------------------------------
// GEMM tile: C[64x64] = A_bf16[64xK] * W_f32[NxK]^T (unchanged this round).
// ---------------------------------------------------------------------------
#define GPAD 68

template <int KTOT, int NVALID>
__device__ __forceinline__ void gemm_tile(const bf16_t* __restrict__ A,
                                          const float* __restrict__ W,
                                          int mBase, int nBase,
                                          float* As, float* Ws,
                                          float acc[4][4]) {
    const int tid = threadIdx.x;
    const int tm = tid >> 4, tn = tid & 15;
    for (int kc = 0; kc < KTOT; kc += 64) {
        for (int i = tid; i < 1024; i += 256) {
            int m = i >> 4, k4 = i & 15;
            ushort4 uv = *(const ushort4*)&A[(size_t)(mBase + m) * KTOT + kc + k4 * 4];
            As[(k4 * 4 + 0) * GPAD + m] = bf2f(uv.x);
            As[(k4 * 4 + 1) * GPAD + m] = bf2f(uv.y);
            As[(k4 * 4 + 2) * GPAD + m] = bf2f(uv.z);
            As[(k4 * 4 + 3) * GPAD + m] = bf2f(uv.w);
        }
        for (int i = tid; i < 1024; i += 256) {
            int n = i >> 4, k4 = i & 15;
            float4 v = make_float4(0.f, 0.f, 0.f, 0.f);
            if (nBase + n < NVALID)
                v = *(const float4*)&W[(size_t)(nBase + n) * KTOT + kc + k4 * 4];
            Ws[(k4 * 4 + 0) * GPAD + n] = v.x;
            Ws[(k4 * 4 + 1) * GPAD + n] = v.y;
            Ws[(k4 * 4 + 2) * GPAD + n] = v.z;
            Ws[(k4 * 4 + 3) * GPAD + n] = v.w;
        }
        __syncthreads();
#pragma unroll 8
        for (int k = 0; k < 64; ++k) {
            float4 a = *(const float4*)&As[k * GPAD + tm * 4];
            float4 b = *(const float4*)&Ws[k * GPAD + tn * 4];
            acc[0][0] += a.x * b.x; acc[0][1] += a.x * b.y; acc[0][2] += a.x * b.z; acc[0][3] += a.x * b.w;
            acc[1][0] += a.y * b.x; acc[1][1] += a.y * b.y; acc[1][2] += a.y * b.z; acc[1][3] += a.y * b.w;
            acc[2][0] += a.z * b.x; acc[2][1] += a.z * b.y; acc[2][2] += a.z * b.z; acc[2][3] += a.z * b.w;
            acc[3][0] += a.w * b.x; acc[3][1] += a.w * b.y; acc[3][2] += a.w * b.z; acc[3][3] += a.w * b.w;
        }
        __syncthreads();
    }
}

__global__ __launch_bounds__(256) void k_gemm_in(const bf16_t* __restrict__ xn,
                                                 const float* __restrict__ inw,
                                                 bf16_t* __restrict__ u_pre,
                                                 bf16_t* __restrict__ z) {
    __shared__ float As[64 * GPAD], Ws[64 * GPAD];
    float acc[4][4] = {};
    int mBase = blockIdx.x * 64, nBase = blockIdx.y * 64;
    gemm_tile<DM, 512>(xn, inw, mBase, nBase, As, Ws, acc);
    int tm = threadIdx.x >> 4, tn = threadIdx.x & 15;
#pragma unroll
    for (int mi = 0; mi < 4; ++mi) {
        int m  = mBase + tm * 4 + mi;
        int ng = nBase + tn * 4;
        ushort4 v;
        v.x = f2bf(acc[mi][0]); v.y = f2bf(acc[mi][1]);
        v.z = f2bf(acc[mi][2]); v.w = f2bf(acc[mi][3]);
        if (ng < DI) *(ushort4*)&u_pre[(size_t)m * DI + ng] = v;
        else         *(ushort4*)&z[(size_t)m * DI + (ng - DI)] = v;
    }
}

__global__ __launch_bounds__(256) void k_gemm_xproj(const bf16_t* __restrict__ u,
                                                    const float* __restrict__ xw,
                                                    float* __restrict__ dbl) {
    __shared__ float As[64 * GPAD], Ws[64 * GPAD];
    float acc[4][4] = {};
    int mBase = blockIdx.x * 64;
    gemm_tile<DI, NDBL>(u, xw, mBase, 0, As, Ws, acc);
    int tm = threadIdx.x >> 4, tn = threadIdx.x & 15;
#pragma unroll
    for (int mi = 0; mi < 4; ++mi) {
        int m  = mBase + tm * 4 + mi;
        int ng = tn * 4;
        if (ng < NDBL) {
            float4 v = make_float4(acc[mi][0], acc[mi][1], acc[mi][2], acc[mi][3]);
            *(float4*)&dbl[(size_t)m * NDBL + ng] = v;
        }
    }
}

__global__ __launch_bounds__(256) void k_gemm_out(const bf16_t* __restrict__ yg,
                                                  const float* __restrict__ ow,
                                                  float* __restrict__ h) {
    __shared__ float As[64 * GPAD], Ws[64 * GPAD];
    float acc[4][4] = {};
    int mBase = blockIdx.x * 64, nBase = blockIdx.y * 64;
    gemm_tile<DI, DM>(yg, ow, mBase, nBase, As, Ws, acc);
    int tm = threadIdx.x >> 4, tn = threadIdx.x & 15;
#pragma unroll
    for (int mi = 0; mi < 4; ++mi) {
        int m  = mBase + tm * 4 + mi;
        int ng = nBase + tn * 4;
        float4 old = *(const float4*)&h[(size_t)m * DM + ng];
        old.x += acc[mi][0]; old.y += acc[mi][1]; old.z += acc[mi][2]; old.w += acc[mi][3];
        *(float4*)&h[(size_t)m * DM + ng] = old;
    }
}

// ---------------------------------------------------------------------------
// Causal depthwise conv (k=4) + SiLU.
// ---------------------------------------------------------------------------
__global__ __launch_bounds__(256) void k_conv(const bf16_t* __restrict__ u_pre,
                                              const float* __restrict__ cw,
                                              const float* __restrict__ cb,
                                              bf16_t* __restrict__ u) {
    int b = blockIdx.y, c0 = blockIdx.x * 64;
    int d = threadIdx.x;
    float w0 = cw[d * 4 + 0], w1 = cw[d * 4 + 1], w2 = cw[d * 4 + 2], w3 = cw[d * 4 + 3];
    float bb = cb[d];
    size_t base = ((size_t)b * Lz) * DI + d;
    float x3 = (c0 >= 3) ? bf2f(u_pre[base + (size_t)(c0 - 3) * DI]) : 0.f;
    float x2 = (c0 >= 2) ? bf2f(u_pre[base + (size_t)(c0 - 2) * DI]) : 0.f;
    float x1 = (c0 >= 1) ? bf2f(u_pre[base + (size_t)(c0 - 1) * DI]) : 0.f;
    for (int t = 0; t < 64; ++t) {
        float x0 = bf2f(u_pre[base + (size_t)(c0 + t) * DI]);
        float conv = bb + w0 * x3 + w1 * x2 + w2 * x1 + w3 * x0;
        float sil = conv * fast_rcp(1.f + __expf(-conv));
        u[base + (size_t)(c0 + t) * DI] = f2bf(sil);
        x3 = x2; x2 = x1; x1 = x0;
    }
}

// ---------------------------------------------------------------------------
// Scan phase 1: per-chunk (P = prod dA, Q = local state), CHT=64.
// dt computed from dbl tile in LDS (float4 reads). Fast path: a[s]=a0*(s+1)
// -> dA chain via repeated multiply; P via exp(a[s]*sum_dt). Generic fallback.
// ---------------------------------------------------------------------------
__global__ __launch_bounds__(256) void k_scan1(const float* __restrict__ dbl,
                                               const bf16_t* __restrict__ u,
                                               const float* __restrict__ dtw,
                                               const float* __restrict__ dtb,
                                               const float* __restrict__ Alog,
                                               float* __restrict__ P,
                                               float* __restrict__ Q) {
    __shared__ float Dt8[CHT * 8];     // 2 KB
    __shared__ float Bs[CHT * DS];     // 4 KB
    int c = blockIdx.x, b = blockIdx.y;
    int d = threadIdx.x;
    size_t tokBase = (size_t)b * Lz + (size_t)c * CHT;
    for (int i = threadIdx.x; i < CHT * NDBL; i += 256) {
        float v = dbl[tokBase * NDBL + i];
        int t = i / NDBL, col = i - t * NDBL;
        if (col < DTR)            Dt8[t * 8 + col] = v;
        else if (col < DTR + DS)  Bs[t * DS + (col - DTR)] = v;
    }
    __syncthreads();
    float w[DTR];
#pragma unroll
    for (int r = 0; r < DTR; ++r) w[r] = dtw[d * DTR + r];
    float bb = dtb[d];
    float a[DS], q[DS];
#pragma unroll
    for (int s = 0; s < DS; ++s) {
        a[s] = -__expf(Alog[d * DS + s]);
        q[s] = 0.f;
    }
    float a0 = a[0];
    bool fast = true;
#pragma unroll
    for (int s = 1; s < DS; ++s) {
        float ref = a0 * (float)(s + 1);
        fast = fast && (fabsf(a[s] - ref) <= 1e-5f * fabsf(ref) + 1e-7f);
    }
    const bf16_t* up = u + tokBase * DI + d;
    float uc[4];
#pragma unroll
    for (int j = 0; j < 4; ++j) uc[j] = bf2f(up[(size_t)j * DI]);
    float sdt = 0.f;
    float p[DS];
#pragma unroll
    for (int s = 0; s < DS; ++s) p[s] = 1.f;

    if (fast) {
        for (int g = 0; g < CHT / 4; ++g) {
            float un[4] = {0.f, 0.f, 0.f, 0.f};
            if (g + 1 < CHT / 4) {
#pragma unroll
                for (int j = 0; j < 4; ++j)
                    un[j] = bf2f(up[(size_t)((g + 1) * 4 + j) * DI]);
            }
#pragma unroll
            for (int j = 0; j < 4; ++j) {
                int t = g * 4 + j;
                float4 r0 = *(const float4*)&Dt8[t * 8];
                float4 r1 = *(const float4*)&Dt8[t * 8 + 4];
                float xv = bb + r0.x*w[0] + r0.y*w[1] + r0.z*w[2] + r0.w*w[3]
                              + r1.x*w[4] + r1.y*w[5] + r1.z*w[6] + r1.w*w[7];
                float dtv = (xv > 20.f) ? xv : __logf(1.f + __expf(xv));
                sdt += dtv;
                float dtu = dtv * uc[j];
                float e1 = __expf(dtv * a0);
                float bv[DS];
                *(float4*)&bv[0]  = *(const float4*)&Bs[t * DS + 0];
                *(float4*)&bv[4]  = *(const float4*)&Bs[t * DS + 4];
                *(float4*)&bv[8]  = *(const float4*)&Bs[t * DS + 8];
                *(float4*)&bv[12] = *(const float4*)&Bs[t * DS + 12];
                float dA = e1;
#pragma unroll
                for (int s = 0; s < DS; ++s) {
                    q[s] = q[s] * dA + dtu * bv[s];
                    dA *= e1;
                }
            }
#pragma unroll
            for (int j = 0; j < 4; ++j) uc[j] = un[j];
        }
#pragma unroll
        for (int s = 0; s < DS; ++s) p[s] = __expf(a[s] * sdt);
    } else {
        for (int g = 0; g < CHT / 4; ++g) {
            float un[4] = {0.f, 0.f, 0.f, 0.f};
            if (g + 1 < CHT / 4) {
#pragma unroll
                for (int j = 0; j < 4; ++j)
                    un[j] = bf2f(up[(size_t)((g + 1) * 4 + j) * DI]);
            }
#pragma unroll
            for (int j = 0; j < 4; ++j) {
                int t = g * 4 + j;
                float4 r0 = *(const float4*)&Dt8[t * 8];
                float4 r1 = *(const float4*)&Dt8[t * 8 + 4];
                float xv = bb + r0.x*w[0] + r0.y*w[1] + r0.z*w[2] + r0.w*w[3]
                              + r1.x*w[4] + r1.y*w[5] + r1.z*w[6] + r1.w*w[7];
                float dtv = (xv > 20.f) ? xv : __logf(1.f + __expf(xv));
                float dtu = dtv * uc[j];
                float bv[DS];
                *(float4*)&bv[0]  = *(const float4*)&Bs[t * DS + 0];
                *(float4*)&bv[4]  = *(const float4*)&Bs[t * DS + 4];
                *(float4*)&bv[8]  = *(const float4*)&Bs[t * DS + 8];
                *(float4*)&bv[12] = *(const float4*)&Bs[t * DS + 12];
#pragma unroll
                for (int s = 0; s < DS; ++s) {
                    float dA = __expf(dtv * a[s]);
                    p[s] *= dA;
                    q[s] = q[s] * dA + dtu * bv[s];
                }
            }
#pragma unroll
            for (int j = 0; j < 4; ++j) uc[j] = un[j];
        }
    }
    size_t o = ((size_t)(b * NCH + c) * DI + d) * DS;
#pragma unroll
    for (int s = 0; s < DS; s += 4) {
        *(float4*)&P[o + s] = make_float4(p[s], p[s+1], p[s+2], p[s+3]);
        *(float4*)&Q[o + s] = make_float4(q[s], q[s+1], q[s+2], q[s+3]);
    }
}

// ---------------------------------------------------------------------------
// Phase 2: scan chunk summaries; P[c] overwritten with entry state.
// Grouped-8 register prefetch (latency-bound: 0.5 waves/SIMD).
// ---------------------------------------------------------------------------
__global__ __launch_bounds__(256) void k_scan2(float* __restrict__ P,
                                               const float* __restrict__ Q) {
    int gid = blockIdx.x * 256 + threadIdx.x;
    int b = gid >> 12, r = gid & 4095;            // DI*DS = 4096
    const size_t stride = (size_t)DI * DS;
    size_t base = (size_t)b * NCH * stride + r;
    float hh = 0.f;
    for (int g = 0; g < NCH / 8; ++g) {
        float pp[8], qq[8];
#pragma unroll
        for (int j = 0; j < 8; ++j) {
            size_t o = base + (size_t)(g * 8 + j) * stride;
            pp[j] = P[o]; qq[j] = Q[o];
        }
#pragma unroll
        for (int j = 0; j < 8; ++j) {
            size_t o = base + (size_t)(g * 8 + j) * stride;
            P[o] = hh;
            hh = pp[j] * hh + qq[j];
        }
    }
}

// ---------------------------------------------------------------------------
// Phase 3: replay with entry state; fuse y = (scan + u*Dp)*silu(z) -> bf16 yg.
// ---------------------------------------------------------------------------
__global__ __launch_bounds__(256) void k_scan3(const float* __restrict__ dbl,
                                               const bf16_t* __restrict__ u,
                                               const bf16_t* __restrict__ z,
                                               const float* __restrict__ dtw,
                                               const float* __restrict__ dtb,
                                               const float* __restrict__ Alog,
                                               const float* __restrict__ Dpv,
                                               const float* __restrict__ H0,
                                               bf16_t* __restrict__ yg) {
    __shared__ float Dt8[CHT * 8];
    __shared__ float Bs[CHT * DS];
    __shared__ float Cs[CHT * DS];
    int c = blockIdx.x, b = blockIdx.y;
    int d = threadIdx.x;
    size_t tokBase = (size_t)b * Lz + (size_t)c * CHT;
    for (int i = threadIdx.x; i < CHT * NDBL; i += 256) {
        float v = dbl[tokBase * NDBL + i];
        int t = i / NDBL, col = i - t * NDBL;
        if (col < DTR)            Dt8[t * 8 + col] = v;
        else if (col < DTR + DS)  Bs[t * DS + (col - DTR)] = v;
        else                      Cs[t * DS + (col - DTR - DS)] = v;
    }
    __syncthreads();
    float w[DTR];
#pragma unroll
    for (int r = 0; r < DTR; ++r) w[r] = dtw[d * DTR + r];
    float bb = dtb[d];
    float a[DS], hh[DS];
    size_t ho = ((size_t)(b * NCH + c) * DI + d) * DS;
#pragma unroll
    for (int s = 0; s < DS; ++s) {
        a[s]  = -__expf(Alog[d * DS + s]);
        hh[s] = H0[ho + s];
    }
    float a0 = a[0];
    bool fast = true;
#pragma unroll
    for (int s = 1; s < DS; ++s) {
        float ref = a0 * (float)(s + 1);
        fast = fast && (fabsf(a[s] - ref) <= 1e-5f * fabsf(ref) + 1e-7f);
    }
    float dp = Dpv[d];
    const bf16_t* up = u + tokBase * DI + d;
    const bf16_t* zp = z + tokBase * DI + d;
    bf16_t* yp = yg + tokBase * DI + d;
    float uc[4], zc[4];
#pragma unroll
    for (int j = 0; j < 4; ++j) {
        uc[j] = bf2f(up[(size_t)j * DI]);
        zc[j] = bf2f(zp[(size_t)j * DI]);
    }
    if (fast) {
        for (int g = 0; g < CHT / 4; ++g) {
            float un[4] = {0,0,0,0}, zn[4] = {0,0,0,0};
            if (g + 1 < CHT / 4) {
#pragma unroll
                for (int j = 0; j < 4; ++j) {
                    un[j] = bf2f(up[(size_t)((g + 1) * 4 + j) * DI]);
                    zn[j] = bf2f(zp[(size_t)((g + 1) * 4 + j) * DI]);
                }
            }
#pragma unroll
            for (int j = 0; j < 4; ++j) {
                int t = g * 4 + j;
                float4 r0 = *(const float4*)&Dt8[t * 8];
                float4 r1 = *(const float4*)&Dt8[t * 8 + 4];
                float xv = bb + r0.x*w[0] + r0.y*w[1] + r0.z*w[2] + r0.w*w[3]
                              + r1.x*w[4] + r1.y*w[5] + r1.z*w[6] + r1.w*w[7];
                float dtv = (xv > 20.f) ? xv : __logf(1.f + __expf(xv));
                float uv = uc[j], zv = zc[j];
                float dtu = dtv * uv;
                float e1 = __expf(dtv * a0);
                float bv[DS], cv[DS];
                *(float4*)&bv[0]  = *(const float4*)&Bs[t * DS + 0];
                *(float4*)&bv[4]  = *(const float4*)&Bs[t * DS + 4];
                *(float4*)&bv[8]  = *(const float4*)&Bs[t * DS + 8];
                *(float4*)&bv[12] = *(const float4*)&Bs[t * DS + 12];
                *(float4*)&cv[0]  = *(const float4*)&Cs[t * DS + 0];
                *(float4*)&cv[4]  = *(const float4*)&Cs[t * DS + 4];
                *(float4*)&cv[8]  = *(const float4*)&Cs[t * DS + 8];
                *(float4*)&cv[12] = *(const float4*)&Cs[t * DS + 12];
                float dA = e1;
                float y = 0.f;
#pragma unroll
                for (int s = 0; s < DS; ++s) {
                    hh[s] = hh[s] * dA + dtu * bv[s];
                    y += hh[s] * cv[s];
                    dA *= e1;
                }
                float sil = zv * fast_rcp(1.f + __expf(-zv));
                yp[(size_t)t * DI] = f2bf((y + uv * dp) * sil);
            }
#pragma unroll
            for (int j = 0; j < 4; ++j) { uc[j] = un[j]; zc[j] = zn[j]; }
        }
    } else {
        for (int g = 0; g < CHT / 4; ++g) {
            float un[4] = {0,0,0,0}, zn[4] = {0,0,0,0};
            if (g + 1 < CHT / 4) {
#pragma unroll
                for (int j = 0; j < 4; ++j) {
                    un[j] = bf2f(up[(size_t)((g + 1) * 4 + j) * DI]);
                    zn[j] = bf2f(zp[(size_t)((g + 1) * 4 + j) * DI]);
                }
            }
#pragma unroll
            for (int j = 0; j < 4; ++j) {
                int t = g * 4 + j;
                float4 r0 = *(const float4*)&Dt8[t * 8];
                float4 r1 = *(const float4*)&Dt8[t * 8 + 4];
                float xv = bb + r0.x*w[0] + r0.y*w[1] + r0.z*w[2] + r0.w*w[3]
                              + r1.x*w[4] + r1.y*w[5] + r1.z*w[6] + r1.w*w[7];
                float dtv = (xv > 20.f) ? xv : __logf(1.f + __expf(xv));
                float uv = uc[j], zv = zc[j];
                float dtu = dtv * uv;
                float bv[DS], cv[DS];
                *(float4*)&bv[0]  = *(const float4*)&Bs[t * DS + 0];
                *(float4*)&bv[4]  = *(const float4*)&Bs[t * DS + 4];
                *(float4*)&bv[8]  = *(const float4*)&Bs[t * DS + 8];
                *(float4*)&bv[12] = *(const float4*)&Bs[t * DS + 12];
                *(float4*)&cv[0]  = *(const float4*)&Cs[t * DS + 0];
                *(float4*)&cv[4]  = *(const float4*)&Cs[t * DS + 4];
                *(float4*)&cv[8]  = *(const float4*)&Cs[t * DS + 8];
                *(float4*)&cv[12] = *(const float4*)&Cs[t * DS + 12];
                float y = 0.f;
#pragma unroll
                for (int s = 0; s < DS; ++s) {
                    float dA = __expf(dtv * a[s]);
                    hh[s] = hh[s] * dA + dtu * bv[s];
                    y += hh[s] * cv[s];
                }
                float sil = zv * fast_rcp(1.f + __expf(-zv));
                yp[(size_t)t * DI] = f2bf((y + uv * dp) * sil);
            }
#pragma unroll
            for (int j = 0; j < 4; ++j) { uc[j] = un[j]; zc[j] = zn[j]; }
        }
    }
}

// ---------------------------------------------------------------------------
__global__ __launch_bounds__(256) void k_final(float* __restrict__ h,
                                               const float* __restrict__ w,
                                               const float* __restrict__ bias,
                                               float* __restrict__ hg) {
    __shared__ float sbuf[DM];
    int t    = blockIdx.x * 16 + (threadIdx.x >> 4);
    int lane = threadIdx.x & 15;
    int b    = t >> 13;
    if (threadIdx.x < DM) sbuf[threadIdx.x] = 0.f;
    __syncthreads();
    float4* hp = (float4*)(h + (size_t)t * DM + lane * 8);
    float4 v0 = hp[0], v1 = hp[1];
    float s = v0.x + v0.y + v0.z + v0.w + v1.x + v1.y + v1.z + v1.w;
    float q = v0.x*v0.x + v0.y*v0.y + v0.z*v0.z + v0.w*v0.w +
              v1.x*v1.x + v1.y*v1.y + v1.z*v1.z + v1.w*v1.w;
#pragma unroll
    for (int off = 1; off < 16; off <<= 1) {
        s += __shfl_xor(s, off);
        q += __shfl_xor(q, off);
    }
    float mean = s * (1.f / DM);
    float var  = q * (1.f / DM) - mean * mean;
    float rstd = rsqrtf(var + 1e-5f);
    const float4* wp = (const float4*)(w + lane * 8);
    const float4* bp = (const float4*)(bias + lane * 8);
    float4 w0 = wp[0], w1 = wp[1], b0 = bp[0], b1 = bp[1];
    float4 o0, o1;
    o0.x = (v0.x - mean) * rstd * w0.x + b0.x;
    o0.y = (v0.y - mean) * rstd * w0.y + b0.y;
    o0.z = (v0.z - mean) * rstd * w0.z + b0.z;
    o0.w = (v0.w - mean) * rstd * w0.w + b0.w;
    o1.x = (v1.x - mean) * rstd * w1.x + b1.x;
    o1.y = (v1.y - mean) * rstd * w1.y + b1.y;
    o1.z = (v1.z - mean) * rstd * w1.z + b1.z;
    o1.w = (v1.w - mean) * rstd * w1.w + b1.w;
    hp[0] = o0; hp[1] = o1;
    int dbase = lane * 8;
    atomicAdd(&sbuf[dbase + 0], o0.x); atomicAdd(&sbuf[dbase + 1], o0.y);
    atomicAdd(&sbuf[dbase + 2], o0.z); atomicAdd(&sbuf[dbase + 3], o0.w);
    atomicAdd(&sbuf[dbase + 4], o1.x); atomicAdd(&sbuf[dbase + 5], o1.y);
    atomicAdd(&sbuf[dbase + 6], o1.z); atomicAdd(&sbuf[dbase + 7], o1.w);
    __syncthreads();
    if (threadIdx.x < DM)
        atomicAdd(&hg[b * DM + threadIdx.x], sbuf[threadIdx.x] * (1.f / Lz));
}

// ---------------------------------------------------------------------------
extern "C" void kernel_launch(void* const* d_in, const int* in_sizes, int n_in,
                              void* d_out, int out_size, void* d_ws, size_t ws_size,
                              hipStream_t stream) {
    const float* x       = (const float*)d_in[0];
    const float* proj_w  = (const float*)d_in[1];
    const float* proj_b  = (const float*)d_in[2];
    const float* ln_w    = (const float*)d_in[3];
    const float* ln_b    = (const float*)d_in[4];
    const float* in_w    = (const float*)d_in[5];
    const float* conv_w  = (const float*)d_in[6];
    const float* conv_b  = (const float*)d_in[7];
    const float* xproj_w = (const float*)d_in[8];
    const float* dt_w    = (const float*)d_in[9];
    const float* dt_b    = (const float*)d_in[10];
    const float* A_log   = (const float*)d_in[11];
    const float* Dp      = (const float*)d_in[12];
    const float* out_w   = (const float*)d_in[13];
    const float* lnout_w = (const float*)d_in[14];
    const float* lnout_b = (const float*)d_in[15];

    float* out = (float*)d_out;
    float* h   = out;                        // [BL][128] lives in d_out
    float* hg  = out + (size_t)BLz * DM;     // [B][128]

    // Workspace layout (~139 MiB). Q aliases xn (dead after k_gemm_in);
    // yg aliases u_pre (dead after k_conv).
    char* ws = (char*)d_ws;
    bf16_t* xn    = (bf16_t*)(ws);                                    // 16 MiB
    bf16_t* u_pre = (bf16_t*)(ws + 16777216ULL);                      // 32 MiB
    bf16_t* z     = (bf16_t*)(ws + 16777216ULL + 33554432ULL);        // 32 MiB
    bf16_t* u     = (bf16_t*)(ws + 16777216ULL + 2*33554432ULL);      // 32 MiB
    float*  dbl   = (float*) (ws + 16777216ULL + 3*33554432ULL);      // 10 MiB
    float*  P     = (float*) (ws + 16777216ULL + 3*33554432ULL + 10485760ULL); // 16 MiB
    float*  Q     = (float*)xn;
    bf16_t* yg    = u_pre;

    k_zero_hg<<<4, 256, 0, stream>>>(hg);
    k_inproj<<<BLz / 2, 256, 0, stream>>>(x, proj_w, proj_b, h);

    for (int i = 0; i < DEPTHN; ++i) {
        k_ln<<<BLz / 16, 256, 0, stream>>>(h, ln_w + i * DM, ln_b + i * DM, xn);
        k_gemm_in<<<dim3(BLz / 64, 8), 256, 0, stream>>>(
            xn, in_w + (size_t)i * 2 * DI * DM, u_pre, z);
        k_conv<<<dim3(Lz / 64, Bz), 256, 0, stream>>>(
            u_pre, conv_w + i * DI * 4, conv_b + i * DI, u);
        k_gemm_xproj<<<dim3(BLz / 64, 1), 256, 0, stream>>>(
            u, xproj_w + (size_t)i * NDBL * DI, dbl);
        k_scan1<<<dim3(NCH, Bz), 256, 0, stream>>>(
            dbl, u, dt_w + i * DI * DTR, dt_b + i * DI, A_log + i * DI * DS, P, Q);
        k_scan2<<<(Bz * DI * DS) / 256, 256, 0, stream>>>(P, Q);
        k_scan3<<<dim3(NCH, Bz), 256, 0, stream>>>(
            dbl, u, z, dt_w + i * DI * DTR, dt_b + i * DI,
            A_log + i * DI * DS, Dp + i * DI, P, yg);
        k_gemm_out<<<dim3(BLz / 64, 2), 256, 0, stream>>>(
            yg, out_w + (size_t)i * DM * DI, h);
    }

    k_final<<<BLz / 16, 256, 0, stream>>>(h, lnout_w, lnout_b, hg);
}

// Round 4
// 1138.355 us; speedup vs baseline: 2.0481x; 1.4659x over previous
//
#include <hip/hip_runtime.h>
#include <hip/hip_bf16.h>
#include <math.h>

// Problem constants (MambaEncoder)
#define Bz     8
#define Lz     8192
#define DM     128      // d_model
#define DI     256      // d_inner
#define DS     16       // d_state
#define DTR    8        // dt_rank
#define NDBL   40       // DTR + 2*DS
#define DEPTHN 4
#define BLz    (Bz*Lz)  // 65536 tokens
#define CHT    64       // scan chunk length
#define NCH    (Lz/CHT) // 128 chunks per sequence

typedef unsigned short bf16_t;
typedef __attribute__((ext_vector_type(8))) __bf16 bf8;
typedef __attribute__((ext_vector_type(4))) float f4;
typedef __attribute__((ext_vector_type(8))) unsigned short us8;

__device__ __forceinline__ float bf2f(bf16_t u) {
    return __uint_as_float(((unsigned)u) << 16);
}
__device__ __forceinline__ bf16_t f2bf(float f) {
    unsigned u = __float_as_uint(f);
    u = u + 0x7FFFu + ((u >> 16) & 1u);   // round-to-nearest-even
    return (bf16_t)(u >> 16);
}
__device__ __forceinline__ float fast_rcp(float x) {
    return __builtin_amdgcn_rcpf(x);
}

// ---------------------------------------------------------------------------
__global__ void k_zero_hg(float* __restrict__ hg) {
    int i = blockIdx.x * 256 + threadIdx.x;
    if (i < Bz * DM) hg[i] = 0.f;
}

// ---------------------------------------------------------------------------
// Convert weights fp32 -> bf16 (xproj padded from 40 to 64 rows with zeros).
// ---------------------------------------------------------------------------
__global__ __launch_bounds__(256) void k_wconv(const float* __restrict__ inw,
                                               const float* __restrict__ ow,
                                               const float* __restrict__ xw,
                                               bf16_t* __restrict__ inwb,
                                               bf16_t* __restrict__ owb,
                                               bf16_t* __restrict__ xwb) {
    int i = blockIdx.x * 256 + threadIdx.x;
    if (i < DEPTHN * 512 * DM) inwb[i] = f2bf(inw[i]);
    if (i < DEPTHN * DM * DI)  owb[i]  = f2bf(ow[i]);
    if (i < DEPTHN * 64 * DI) {
        int layer = i >> 14, rk = i & 16383, r = rk >> 8, k = rk & 255;
        xwb[i] = (r < NDBL) ? f2bf(xw[((size_t)layer * NDBL + r) * DI + k]) : (bf16_t)0;
    }
}

// ---------------------------------------------------------------------------
__global__ __launch_bounds__(256) void k_inproj(const float* __restrict__ x,
                                                const float* __restrict__ pw,
                                                const float* __restrict__ pb,
                                                float* __restrict__ h) {
    int t = blockIdx.x * 2 + (threadIdx.x >> 7);
    int d = threadIdx.x & 127;
    int b = t >> 13, l = t & (Lz - 1);
    float acc = pb[d];
#pragma unroll
    for (int c = 0; c < 3; ++c)
        acc += x[(size_t)(b * 3 + c) * Lz + l] * pw[d * 3 + c];
    h[(size_t)t * DM + d] = acc;
}

// ---------------------------------------------------------------------------
__global__ __launch_bounds__(256) void k_ln(const float* __restrict__ h,
                                            const float* __restrict__ w,
                                            const float* __restrict__ bias,
                                            bf16_t* __restrict__ xn) {
    int t    = blockIdx.x * 16 + (threadIdx.x >> 4);
    int lane = threadIdx.x & 15;
    const float4* hp = (const float4*)(h + (size_t)t * DM + lane * 8);
    float4 v0 = hp[0], v1 = hp[1];
    float s = v0.x + v0.y + v0.z + v0.w + v1.x + v1.y + v1.z + v1.w;
    float q = v0.x*v0.x + v0.y*v0.y + v0.z*v0.z + v0.w*v0.w +
              v1.x*v1.x + v1.y*v1.y + v1.z*v1.z + v1.w*v1.w;
#pragma unroll
    for (int off = 1; off < 16; off <<= 1) {
        s += __shfl_xor(s, off);
        q += __shfl_xor(q, off);
    }
    float mean = s * (1.f / DM);
    float var  = q * (1.f / DM) - mean * mean;
    float rstd = rsqrtf(var + 1e-5f);
    const float4* wp = (const float4*)(w + lane * 8);
    const float4* bp = (const float4*)(bias + lane * 8);
    float4 w0 = wp[0], w1 = wp[1], b0 = bp[0], b1 = bp[1];
    ushort4 o0, o1;
    o0.x = f2bf((v0.x - mean) * rstd * w0.x + b0.x);
    o0.y = f2bf((v0.y - mean) * rstd * w0.y + b0.y);
    o0.z = f2bf((v0.z - mean) * rstd * w0.z + b0.z);
    o0.w = f2bf((v0.w - mean) * rstd * w0.w + b0.w);
    o1.x = f2bf((v1.x - mean) * rstd * w1.x + b1.x);
    o1.y = f2bf((v1.y - mean) * rstd * w1.y + b1.y);
    o1.z = f2bf((v1.z - mean) * rstd * w1.z + b1.z);
    o1.w = f2bf((v1.w - mean) * rstd * w1.w + b1.w);
    ushort4* op = (ushort4*)(xn + (size_t)t * DM + lane * 8);
    op[0] = o0; op[1] = o1;
}

// ---------------------------------------------------------------------------
// MFMA GEMM 1: [M x 512] = xn[M x 128] @ in_w^T. Block: 64(M) x 256(N).
// 4 waves as 2x2; each wave 32(M) x 128(N) via 2x8 16x16x32 tiles.
// Epilogue through LDS (bf16, row pad 264) for coalesced 16B stores.
// ---------------------------------------------------------------------------
#define PADI 264
__global__ __launch_bounds__(256) void k_mfma_in(const bf16_t* __restrict__ A,
                                                 const bf16_t* __restrict__ Wb,
                                                 bf16_t* __restrict__ u_pre,
                                                 bf16_t* __restrict__ z) {
    __shared__ bf16_t tile[64 * PADI];
    int wave = threadIdx.x >> 6, lane = threadIdx.x & 63;
    int lr = lane & 15, lq = lane >> 4;
    int mBase = blockIdx.x * 64;
    int nBase = blockIdx.y * 256;
    int wm = (wave & 1) * 32, wn = (wave >> 1) * 128;
    f4 zf = {0.f, 0.f, 0.f, 0.f};
    f4 acc[2][8];
#pragma unroll
    for (int mi = 0; mi < 2; ++mi)
#pragma unroll
        for (int ni = 0; ni < 8; ++ni) acc[mi][ni] = zf;
    const bf16_t* Ap = A + (size_t)(mBase + wm + lr) * DM + lq * 8;
    const bf16_t* Bp = Wb + (size_t)(nBase + wn + lr) * DM + lq * 8;
#pragma unroll
    for (int kk = 0; kk < DM; kk += 32) {
        bf8 af[2], bq[8];
        af[0] = *(const bf8*)(Ap + kk);
        af[1] = *(const bf8*)(Ap + 16 * DM + kk);
#pragma unroll
        for (int ni = 0; ni < 8; ++ni)
            bq[ni] = *(const bf8*)(Bp + (size_t)ni * 16 * DM + kk);
#pragma unroll
        for (int mi = 0; mi < 2; ++mi)
#pragma unroll
            for (int ni = 0; ni < 8; ++ni)
                acc[mi][ni] = __builtin_amdgcn_mfma_f32_16x16x32_bf16(
                    af[mi], bq[ni], acc[mi][ni], 0, 0, 0);
    }
#pragma unroll
    for (int mi = 0; mi < 2; ++mi)
#pragma unroll
        for (int ni = 0; ni < 8; ++ni)
#pragma unroll
            for (int r = 0; r < 4; ++r)
                tile[(wm + mi * 16 + lq * 4 + r) * PADI + wn + ni * 16 + lr] =
                    f2bf(acc[mi][ni][r]);
    __syncthreads();
    bf16_t* dst = (blockIdx.y == 0) ? u_pre : z;
    for (int i = threadIdx.x; i < 2048; i += 256) {
        int row = i >> 5, col = (i & 31) * 8;
        us8 v = *(const us8*)&tile[row * PADI + col];
        *(us8*)&dst[(size_t)(mBase + row) * DI + col] = v;
    }
}

// ---------------------------------------------------------------------------
// MFMA GEMM 2: h[M x 128] += yg[M x 256] @ out_w^T. Block 64(M) x 128(N);
// wave m = wave*16; each wave 1x8 tiles. Epilogue LDS fp32 (pad 132).
// ---------------------------------------------------------------------------
__global__ __launch_bounds__(256) void k_mfma_out(const bf16_t* __restrict__ A,
                                                  const bf16_t* __restrict__ Wb,
                                                  float* __restrict__ h) {
    __shared__ float tile[64 * 132];
    int wave = threadIdx.x >> 6, lane = threadIdx.x & 63;
    int lr = lane & 15, lq = lane >> 4;
    int mBase = blockIdx.x * 64;
    int wm = wave * 16;
    f4 zf = {0.f, 0.f, 0.f, 0.f};
    f4 acc[8];
#pragma unroll
    for (int ni = 0; ni < 8; ++ni) acc[ni] = zf;
    const bf16_t* Ap = A + (size_t)(mBase + wm + lr) * DI + lq * 8;
    const bf16_t* Bp = Wb + (size_t)lr * DI + lq * 8;
#pragma unroll
    for (int kk = 0; kk < DI; kk += 32) {
        bf8 af = *(const bf8*)(Ap + kk);
        bf8 bq[8];
#pragma unroll
        for (int ni = 0; ni < 8; ++ni)
            bq[ni] = *(const bf8*)(Bp + (size_t)ni * 16 * DI + kk);
#pragma unroll
        for (int ni = 0; ni < 8; ++ni)
            acc[ni] = __builtin_amdgcn_mfma_f32_16x16x32_bf16(
                af, bq[ni], acc[ni], 0, 0, 0);
    }
#pragma unroll
    for (int ni = 0; ni < 8; ++ni)
#pragma unroll
        for (int r = 0; r < 4; ++r)
            tile[(wm + lq * 4 + r) * 132 + ni * 16 + lr] = acc[ni][r];
    __syncthreads();
    for (int i = threadIdx.x; i < 2048; i += 256) {
        int row = i >> 5, col = (i & 31) * 4;
        float4 v = *(const float4*)&tile[row * 132 + col];
        float4 old = *(const float4*)&h[(size_t)(mBase + row) * DM + col];
        old.x += v.x; old.y += v.y; old.z += v.z; old.w += v.w;
        *(float4*)&h[(size_t)(mBase + row) * DM + col] = old;
    }
}

// ---------------------------------------------------------------------------
// MFMA GEMM 3: dbl[M x 40] = u[M x 256] @ xproj_w^T (padded to 64 cols).
// Block 64(M); wave m = wave*16, 1x4 tiles. Epilogue LDS fp32 (pad 68).
// ---------------------------------------------------------------------------
__global__ __launch_bounds__(256) void k_mfma_xp(const bf16_t* __restrict__ A,
                                                 const bf16_t* __restrict__ Wb,
                                                 float* __restrict__ dbl) {
    __shared__ float tile[64 * 68];
    int wave = threadIdx.x >> 6, lane = threadIdx.x & 63;
    int lr = lane & 15, lq = lane >> 4;
    int mBase = blockIdx.x * 64;
    int wm = wave * 16;
    f4 zf = {0.f, 0.f, 0.f, 0.f};
    f4 acc[4];
#pragma unroll
    for (int ni = 0; ni < 4; ++ni) acc[ni] = zf;
    const bf16_t* Ap = A + (size_t)(mBase + wm + lr) * DI + lq * 8;
    const bf16_t* Bp = Wb + (size_t)lr * DI + lq * 8;
#pragma unroll
    for (int kk = 0; kk < DI; kk += 32) {
        bf8 af = *(const bf8*)(Ap + kk);
        bf8 bq[4];
#pragma unroll
        for (int ni = 0; ni < 4; ++ni)
            bq[ni] = *(const bf8*)(Bp + (size_t)ni * 16 * DI + kk);
#pragma unroll
        for (int ni = 0; ni < 4; ++ni)
            acc[ni] = __builtin_amdgcn_mfma_f32_16x16x32_bf16(
                af, bq[ni], acc[ni], 0, 0, 0);
    }
#pragma unroll
    for (int ni = 0; ni < 4; ++ni)
#pragma unroll
        for (int r = 0; r < 4; ++r)
            tile[(wm + lq * 4 + r) * 68 + ni * 16 + lr] = acc[ni][r];
    __syncthreads();
    int row = threadIdx.x >> 2, cs = (threadIdx.x & 3) * 10;
    float* dst = &dbl[(size_t)(mBase + row) * NDBL + cs];
    const float* src = &tile[row * 68 + cs];
#pragma unroll
    for (int j = 0; j < 10; ++j) dst[j] = src[j];
}

// ---------------------------------------------------------------------------
// Causal depthwise conv (k=4) + SiLU.
// ---------------------------------------------------------------------------
__global__ __launch_bounds__(256) void k_conv(const bf16_t* __restrict__ u_pre,
                                              const float* __restrict__ cw,
                                              const float* __restrict__ cb,
                                              bf16_t* __restrict__ u) {
    int b = blockIdx.y, c0 = blockIdx.x * 64;
    int d = threadIdx.x;
    float w0 = cw[d * 4 + 0], w1 = cw[d * 4 + 1], w2 = cw[d * 4 + 2], w3 = cw[d * 4 + 3];
    float bb = cb[d];
    size_t base = ((size_t)b * Lz) * DI + d;
    float x3 = (c0 >= 3) ? bf2f(u_pre[base + (size_t)(c0 - 3) * DI]) : 0.f;
    float x2 = (c0 >= 2) ? bf2f(u_pre[base + (size_t)(c0 - 2) * DI]) : 0.f;
    float x1 = (c0 >= 1) ? bf2f(u_pre[base + (size_t)(c0 - 1) * DI]) : 0.f;
    for (int t = 0; t < 64; ++t) {
        float x0 = bf2f(u_pre[base + (size_t)(c0 + t) * DI]);
        float conv = bb + w0 * x3 + w1 * x2 + w2 * x1 + w3 * x0;
        float sil = conv * fast_rcp(1.f + __expf(-conv));
        u[base + (size_t)(c0 + t) * DI] = f2bf(sil);
        x3 = x2; x2 = x1; x1 = x0;
    }
}

// ---------------------------------------------------------------------------
// Scan phase 1: per-chunk (P = prod dA, Q = local state), CHT=64.
// ---------------------------------------------------------------------------
__global__ __launch_bounds__(256) void k_scan1(const float* __restrict__ dbl,
                                               const bf16_t* __restrict__ u,
                                               const float* __restrict__ dtw,
                                               const float* __restrict__ dtb,
                                               const float* __restrict__ Alog,
                                               float* __restrict__ P,
                                               float* __restrict__ Q) {
    __shared__ float Dt8[CHT * 8];
    __shared__ float Bs[CHT * DS];
    int c = blockIdx.x, b = blockIdx.y;
    int d = threadIdx.x;
    size_t tokBase = (size_t)b * Lz + (size_t)c * CHT;
    for (int i = threadIdx.x; i < CHT * NDBL; i += 256) {
        float v = dbl[tokBase * NDBL + i];
        int t = i / NDBL, col = i - t * NDBL;
        if (col < DTR)            Dt8[t * 8 + col] = v;
        else if (col < DTR + DS)  Bs[t * DS + (col - DTR)] = v;
    }
    __syncthreads();
    float w[DTR];
#pragma unroll
    for (int r = 0; r < DTR; ++r) w[r] = dtw[d * DTR + r];
    float bb = dtb[d];
    float a[DS], q[DS];
#pragma unroll
    for (int s = 0; s < DS; ++s) {
        a[s] = -__expf(Alog[d * DS + s]);
        q[s] = 0.f;
    }
    float a0 = a[0];
    bool fast = true;
#pragma unroll
    for (int s = 1; s < DS; ++s) {
        float ref = a0 * (float)(s + 1);
        fast = fast && (fabsf(a[s] - ref) <= 1e-5f * fabsf(ref) + 1e-7f);
    }
    const bf16_t* up = u + tokBase * DI + d;
    float uc[4];
#pragma unroll
    for (int j = 0; j < 4; ++j) uc[j] = bf2f(up[(size_t)j * DI]);
    float sdt = 0.f;
    float p[DS];
#pragma unroll
    for (int s = 0; s < DS; ++s) p[s] = 1.f;

    if (fast) {
        for (int g = 0; g < CHT / 4; ++g) {
            float un[4] = {0.f, 0.f, 0.f, 0.f};
            if (g + 1 < CHT / 4) {
#pragma unroll
                for (int j = 0; j < 4; ++j)
                    un[j] = bf2f(up[(size_t)((g + 1) * 4 + j) * DI]);
            }
#pragma unroll
            for (int j = 0; j < 4; ++j) {
                int t = g * 4 + j;
                float4 r0 = *(const float4*)&Dt8[t * 8];
                float4 r1 = *(const float4*)&Dt8[t * 8 + 4];
                float xv = bb + r0.x*w[0] + r0.y*w[1] + r0.z*w[2] + r0.w*w[3]
                              + r1.x*w[4] + r1.y*w[5] + r1.z*w[6] + r1.w*w[7];
                float dtv = (xv > 20.f) ? xv : __logf(1.f + __expf(xv));
                sdt += dtv;
                float dtu = dtv * uc[j];
                float e1 = __expf(dtv * a0);
                float bv[DS];
                *(float4*)&bv[0]  = *(const float4*)&Bs[t * DS + 0];
                *(float4*)&bv[4]  = *(const float4*)&Bs[t * DS + 4];
                *(float4*)&bv[8]  = *(const float4*)&Bs[t * DS + 8];
                *(float4*)&bv[12] = *(const float4*)&Bs[t * DS + 12];
                float dA = e1;
#pragma unroll
                for (int s = 0; s < DS; ++s) {
                    q[s] = q[s] * dA + dtu * bv[s];
                    dA *= e1;
                }
            }
#pragma unroll
            for (int j = 0; j < 4; ++j) uc[j] = un[j];
        }
#pragma unroll
        for (int s = 0; s < DS; ++s) p[s] = __expf(a[s] * sdt);
    } else {
        for (int g = 0; g < CHT / 4; ++g) {
            float un[4] = {0.f, 0.f, 0.f, 0.f};
            if (g + 1 < CHT / 4) {
#pragma unroll
                for (int j = 0; j < 4; ++j)
                    un[j] = bf2f(up[(size_t)((g + 1) * 4 + j) * DI]);
            }
#pragma unroll
            for (int j = 0; j < 4; ++j) {
                int t = g * 4 + j;
                float4 r0 = *(const float4*)&Dt8[t * 8];
                float4 r1 = *(const float4*)&Dt8[t * 8 + 4];
                float xv = bb + r0.x*w[0] + r0.y*w[1] + r0.z*w[2] + r0.w*w[3]
                              + r1.x*w[4] + r1.y*w[5] + r1.z*w[6] + r1.w*w[7];
                float dtv = (xv > 20.f) ? xv : __logf(1.f + __expf(xv));
                float dtu = dtv * uc[j];
                float bv[DS];
                *(float4*)&bv[0]  = *(const float4*)&Bs[t * DS + 0];
                *(float4*)&bv[4]  = *(const float4*)&Bs[t * DS + 4];
                *(float4*)&bv[8]  = *(const float4*)&Bs[t * DS + 8];
                *(float4*)&bv[12] = *(const float4*)&Bs[t * DS + 12];
#pragma unroll
                for (int s = 0; s < DS; ++s) {
                    float dA = __expf(dtv * a[s]);
                    p[s] *= dA;
                    q[s] = q[s] * dA + dtu * bv[s];
                }
            }
#pragma unroll
            for (int j = 0; j < 4; ++j) uc[j] = un[j];
        }
    }
    size_t o = ((size_t)(b * NCH + c) * DI + d) * DS;
#pragma unroll
    for (int s = 0; s < DS; s += 4) {
        *(float4*)&P[o + s] = make_float4(p[s], p[s+1], p[s+2], p[s+3]);
        *(float4*)&Q[o + s] = make_float4(q[s], q[s+1], q[s+2], q[s+3]);
    }
}

// ---------------------------------------------------------------------------
__global__ __launch_bounds__(256) void k_scan2(float* __restrict__ P,
                                               const float* __restrict__ Q) {
    int gid = blockIdx.x * 256 + threadIdx.x;
    int b = gid >> 12, r = gid & 4095;            // DI*DS = 4096
    const size_t stride = (size_t)DI * DS;
    size_t base = (size_t)b * NCH * stride + r;
    float hh = 0.f;
    for (int g = 0; g < NCH / 8; ++g) {
        float pp[8], qq[8];
#pragma unroll
        for (int j = 0; j < 8; ++j) {
            size_t o = base + (size_t)(g * 8 + j) * stride;
            pp[j] = P[o]; qq[j] = Q[o];
        }
#pragma unroll
        for (int j = 0; j < 8; ++j) {
            size_t o = base + (size_t)(g * 8 + j) * stride;
            P[o] = hh;
            hh = pp[j] * hh + qq[j];
        }
    }
}

// ---------------------------------------------------------------------------
__global__ __launch_bounds__(256) void k_scan3(const float* __restrict__ dbl,
                                               const bf16_t* __restrict__ u,
                                               const bf16_t* __restrict__ z,
                                               const float* __restrict__ dtw,
                                               const float* __restrict__ dtb,
                                               const float* __restrict__ Alog,
                                               const float* __restrict__ Dpv,
                                               const float* __restrict__ H0,
                                               bf16_t* __restrict__ yg) {
    __shared__ float Dt8[CHT * 8];
    __shared__ float Bs[CHT * DS];
    __shared__ float Cs[CHT * DS];
    int c = blockIdx.x, b = blockIdx.y;
    int d = threadIdx.x;
    size_t tokBase = (size_t)b * Lz + (size_t)c * CHT;
    for (int i = threadIdx.x; i < CHT * NDBL; i += 256) {
        float v = dbl[tokBase * NDBL + i];
        int t = i / NDBL, col = i - t * NDBL;
        if (col < DTR)            Dt8[t * 8 + col] = v;
        else if (col < DTR + DS)  Bs[t * DS + (col - DTR)] = v;
        else                      Cs[t * DS + (col - DTR - DS)] = v;
    }
    __syncthreads();
    float w[DTR];
#pragma unroll
    for (int r = 0; r < DTR; ++r) w[r] = dtw[d * DTR + r];
    float bb = dtb[d];
    float a[DS], hh[DS];
    size_t ho = ((size_t)(b * NCH + c) * DI + d) * DS;
#pragma unroll
    for (int s = 0; s < DS; ++s) {
        a[s]  = -__expf(Alog[d * DS + s]);
        hh[s] = H0[ho + s];
    }
    float a0 = a[0];
    bool fast = true;
#pragma unroll
    for (int s = 1; s < DS; ++s) {
        float ref = a0 * (float)(s + 1);
        fast = fast && (fabsf(a[s] - ref) <= 1e-5f * fabsf(ref) + 1e-7f);
    }
    float dp = Dpv[d];
    const bf16_t* up = u + tokBase * DI + d;
    const bf16_t* zp = z + tokBase * DI + d;
    bf16_t* yp = yg + tokBase * DI + d;
    float uc[4], zc[4];
#pragma unroll
    for (int j = 0; j < 4; ++j) {
        uc[j] = bf2f(up[(size_t)j * DI]);
        zc[j] = bf2f(zp[(size_t)j * DI]);
    }
    if (fast) {
        for (int g = 0; g < CHT / 4; ++g) {
            float un[4] = {0,0,0,0}, zn[4] = {0,0,0,0};
            if (g + 1 < CHT / 4) {
#pragma unroll
                for (int j = 0; j < 4; ++j) {
                    un[j] = bf2f(up[(size_t)((g + 1) * 4 + j) * DI]);
                    zn[j] = bf2f(zp[(size_t)((g + 1) * 4 + j) * DI]);
                }
            }
#pragma unroll
            for (int j = 0; j < 4; ++j) {
                int t = g * 4 + j;
                float4 r0 = *(const float4*)&Dt8[t * 8];
                float4 r1 = *(const float4*)&Dt8[t * 8 + 4];
                float xv = bb + r0.x*w[0] + r0.y*w[1] + r0.z*w[2] + r0.w*w[3]
                              + r1.x*w[4] + r1.y*w[5] + r1.z*w[6] + r1.w*w[7];
                float dtv = (xv > 20.f) ? xv : __logf(1.f + __expf(xv));
                float uv = uc[j], zv = zc[j];
                float dtu = dtv * uv;
                float e1 = __expf(dtv * a0);
                float bv[DS], cv[DS];
                *(float4*)&bv[0]  = *(const float4*)&Bs[t * DS + 0];
                *(float4*)&bv[4]  = *(const float4*)&Bs[t * DS + 4];
                *(float4*)&bv[8]  = *(const float4*)&Bs[t * DS + 8];
                *(float4*)&bv[12] = *(const float4*)&Bs[t * DS + 12];
                *(float4*)&cv[0]  = *(const float4*)&Cs[t * DS + 0];
                *(float4*)&cv[4]  = *(const float4*)&Cs[t * DS + 4];
                *(float4*)&cv[8]  = *(const float4*)&Cs[t * DS + 8];
                *(float4*)&cv[12] = *(const float4*)&Cs[t * DS + 12];
                float dA = e1;
                float y = 0.f;
#pragma unroll
                for (int s = 0; s < DS; ++s) {
                    hh[s] = hh[s] * dA + dtu * bv[s];
                    y += hh[s] * cv[s];
                    dA *= e1;
                }
                float sil = zv * fast_rcp(1.f + __expf(-zv));
                yp[(size_t)t * DI] = f2bf((y + uv * dp) * sil);
            }
#pragma unroll
            for (int j = 0; j < 4; ++j) { uc[j] = un[j]; zc[j] = zn[j]; }
        }
    } else {
        for (int g = 0; g < CHT / 4; ++g) {
            float un[4] = {0,0,0,0}, zn[4] = {0,0,0,0};
            if (g + 1 < CHT / 4) {
#pragma unroll
                for (int j = 0; j < 4; ++j) {
                    un[j] = bf2f(up[(size_t)((g + 1) * 4 + j) * DI]);
                    zn[j] = bf2f(zp[(size_t)((g + 1) * 4 + j) * DI]);
                }
            }
#pragma unroll
            for (int j = 0; j < 4; ++j) {
                int t = g * 4 + j;
                float4 r0 = *(const float4*)&Dt8[t * 8];
                float4 r1 = *(const float4*)&Dt8[t * 8 + 4];
                float xv = bb + r0.x*w[0] + r0.y*w[1] + r0.z*w[2] + r0.w*w[3]
                              + r1.x*w[4] + r1.y*w[5] + r1.z*w[6] + r1.w*w[7];
                float dtv = (xv > 20.f) ? xv : __logf(1.f + __expf(xv));
                float uv = uc[j], zv = zc[j];
                float dtu = dtv * uv;
                float bv[DS], cv[DS];
                *(float4*)&bv[0]  = *(const float4*)&Bs[t * DS + 0];
                *(float4*)&bv[4]  = *(const float4*)&Bs[t * DS + 4];
                *(float4*)&bv[8]  = *(const float4*)&Bs[t * DS + 8];
                *(float4*)&bv[12] = *(const float4*)&Bs[t * DS + 12];
                *(float4*)&cv[0]  = *(const float4*)&Cs[t * DS + 0];
                *(float4*)&cv[4]  = *(const float4*)&Cs[t * DS + 4];
                *(float4*)&cv[8]  = *(const float4*)&Cs[t * DS + 8];
                *(float4*)&cv[12] = *(const float4*)&Cs[t * DS + 12];
                float y = 0.f;
#pragma unroll
                for (int s = 0; s < DS; ++s) {
                    float dA = __expf(dtv * a[s]);
                    hh[s] = hh[s] * dA + dtu * bv[s];
                    y += hh[s] * cv[s];
                }
                float sil = zv * fast_rcp(1.f + __expf(-zv));
                yp[(size_t)t * DI] = f2bf((y + uv * dp) * sil);
            }
#pragma unroll
            for (int j = 0; j < 4; ++j) { uc[j] = un[j]; zc[j] = zn[j]; }
        }
    }
}

// ---------------------------------------------------------------------------
__global__ __launch_bounds__(256) void k_final(float* __restrict__ h,
                                               const float* __restrict__ w,
                                               const float* __restrict__ bias,
                                               float* __restrict__ hg) {
    __shared__ float sbuf[DM];
    int t    = blockIdx.x * 16 + (threadIdx.x >> 4);
    int lane = threadIdx.x & 15;
    int b    = t >> 13;
    if (threadIdx.x < DM) sbuf[threadIdx.x] = 0.f;
    __syncthreads();
    float4* hp = (float4*)(h + (size_t)t * DM + lane * 8);
    float4 v0 = hp[0], v1 = hp[1];
    float s = v0.x + v0.y + v0.z + v0.w + v1.x + v1.y + v1.z + v1.w;
    float q = v0.x*v0.x + v0.y*v0.y + v0.z*v0.z + v0.w*v0.w +
              v1.x*v1.x + v1.y*v1.y + v1.z*v1.z + v1.w*v1.w;
#pragma unroll
    for (int off = 1; off < 16; off <<= 1) {
        s += __shfl_xor(s, off);
        q += __shfl_xor(q, off);
    }
    float mean = s * (1.f / DM);
    float var  = q * (1.f / DM) - mean * mean;
    float rstd = rsqrtf(var + 1e-5f);
    const float4* wp = (const float4*)(w + lane * 8);
    const float4* bp = (const float4*)(bias + lane * 8);
    float4 w0 = wp[0], w1 = wp[1], b0 = bp[0], b1 = bp[1];
    float4 o0, o1;
    o0.x = (v0.x - mean) * rstd * w0.x + b0.x;
    o0.y = (v0.y - mean) * rstd * w0.y + b0.y;
    o0.z = (v0.z - mean) * rstd * w0.z + b0.z;
    o0.w = (v0.w - mean) * rstd * w0.w + b0.w;
    o1.x = (v1.x - mean) * rstd * w1.x + b1.x;
    o1.y = (v1.y - mean) * rstd * w1.y + b1.y;
    o1.z = (v1.z - mean) * rstd * w1.z + b1.z;
    o1.w = (v1.w - mean) * rstd * w1.w + b1.w;
    hp[0] = o0; hp[1] = o1;
    int dbase = lane * 8;
    atomicAdd(&sbuf[dbase + 0], o0.x); atomicAdd(&sbuf[dbase + 1], o0.y);
    atomicAdd(&sbuf[dbase + 2], o0.z); atomicAdd(&sbuf[dbase + 3], o0.w);
    atomicAdd(&sbuf[dbase + 4], o1.x); atomicAdd(&sbuf[dbase + 5], o1.y);
    atomicAdd(&sbuf[dbase + 6], o1.z); atomicAdd(&sbuf[dbase + 7], o1.w);
    __syncthreads();
    if (threadIdx.x < DM)
        atomicAdd(&hg[b * DM + threadIdx.x], sbuf[threadIdx.x] * (1.f / Lz));
}

// ---------------------------------------------------------------------------
extern "C" void kernel_launch(void* const* d_in, const int* in_sizes, int n_in,
                              void* d_out, int out_size, void* d_ws, size_t ws_size,
                              hipStream_t stream) {
    const float* x       = (const float*)d_in[0];
    const float* proj_w  = (const float*)d_in[1];
    const float* proj_b  = (const float*)d_in[2];
    const float* ln_w    = (const float*)d_in[3];
    const float* ln_b    = (const float*)d_in[4];
    const float* in_w    = (const float*)d_in[5];
    const float* conv_w  = (const float*)d_in[6];
    const float* conv_b  = (const float*)d_in[7];
    const float* xproj_w = (const float*)d_in[8];
    const float* dt_w    = (const float*)d_in[9];
    const float* dt_b    = (const float*)d_in[10];
    const float* A_log   = (const float*)d_in[11];
    const float* Dp      = (const float*)d_in[12];
    const float* out_w   = (const float*)d_in[13];
    const float* lnout_w = (const float*)d_in[14];
    const float* lnout_b = (const float*)d_in[15];

    float* out = (float*)d_out;
    float* h   = out;                        // [BL][128] lives in d_out
    float* hg  = out + (size_t)BLz * DM;     // [B][128]

    // Workspace layout (~139 MiB). Q aliases xn; yg aliases u_pre.
    char* ws = (char*)d_ws;
    bf16_t* xn    = (bf16_t*)(ws);                                    // 16 MiB
    bf16_t* u_pre = (bf16_t*)(ws + 16777216ULL);                      // 32 MiB
    bf16_t* z     = (bf16_t*)(ws + 50331648ULL);                      // 32 MiB
    bf16_t* u     = (bf16_t*)(ws + 83886080ULL);                      // 32 MiB
    float*  dbl   = (float*) (ws + 117440512ULL);                     // 10 MiB
    float*  P     = (float*) (ws + 127926272ULL);                     // 16 MiB
    bf16_t* inwb  = (bf16_t*)(ws + 144703488ULL);                     // 512 KiB
    bf16_t* owb   = (bf16_t*)(ws + 145227776ULL);                     // 256 KiB
    bf16_t* xwb   = (bf16_t*)(ws + 145489920ULL);                     // 128 KiB
    float*  Q     = (float*)xn;
    bf16_t* yg    = u_pre;

    k_zero_hg<<<4, 256, 0, stream>>>(hg);
    k_wconv<<<1024, 256, 0, stream>>>(in_w, out_w, xproj_w, inwb, owb, xwb);
    k_inproj<<<BLz / 2, 256, 0, stream>>>(x, proj_w, proj_b, h);

    for (int i = 0; i < DEPTHN; ++i) {
        k_ln<<<BLz / 16, 256, 0, stream>>>(h, ln_w + i * DM, ln_b + i * DM, xn);
        k_mfma_in<<<dim3(BLz / 64, 2), 256, 0, stream>>>(
            xn, inwb + (size_t)i * 512 * DM, u_pre, z);
        k_conv<<<dim3(Lz / 64, Bz), 256, 0, stream>>>(
            u_pre, conv_w + i * DI * 4, conv_b + i * DI, u);
        k_mfma_xp<<<BLz / 64, 256, 0, stream>>>(
            u, xwb + (size_t)i * 64 * DI, dbl);
        k_scan1<<<dim3(NCH, Bz), 256, 0, stream>>>(
            dbl, u, dt_w + i * DI * DTR, dt_b + i * DI, A_log + i * DI * DS, P, Q);
        k_scan2<<<(Bz * DI * DS) / 256, 256, 0, stream>>>(P, Q);
        k_scan3<<<dim3(NCH, Bz), 256, 0, stream>>>(
            dbl, u, z, dt_w + i * DI * DTR, dt_b + i * DI,
            A_log + i * DI * DS, Dp + i * DI, P, yg);
        k_mfma_out<<<BLz / 64, 256, 0, stream>>>(
            yg, owb + (size_t)i * DM * DI, h);
    }

    k_final<<<BLz / 16, 256, 0, stream>>>(h, lnout_w, lnout_b, hg);
}

// Round 5
// 1090.050 us; speedup vs baseline: 2.1389x; 1.0443x over previous
//
#include <hip/hip_runtime.h>
#include <hip/hip_bf16.h>
#include <math.h>

// Problem constants (MambaEncoder)
#define Bz     8
#define Lz     8192
#define DM     128      // d_model
#define DI     256      // d_inner
#define DS     16       // d_state
#define DTR    8        // dt_rank
#define NDBL   40       // DTR + 2*DS
#define DEPTHN 4
#define BLz    (Bz*Lz)  // 65536 tokens
#define CHT    64       // scan chunk length == GEMM M-tile
#define NCH    (Lz/CHT) // 128 chunks per sequence

typedef unsigned short bf16_t;
typedef __attribute__((ext_vector_type(8))) __bf16 bf8;
typedef __attribute__((ext_vector_type(4))) float f4;
typedef __attribute__((ext_vector_type(8))) unsigned short us8;

__device__ __forceinline__ float bf2f(bf16_t u) {
    return __uint_as_float(((unsigned)u) << 16);
}
__device__ __forceinline__ bf16_t f2bf(float f) {
    unsigned u = __float_as_uint(f);
    u = u + 0x7FFFu + ((u >> 16) & 1u);   // round-to-nearest-even
    return (bf16_t)(u >> 16);
}
__device__ __forceinline__ float fast_rcp(float x) {
    return __builtin_amdgcn_rcpf(x);
}

// ---------------------------------------------------------------------------
__global__ void k_zero_hg(float* __restrict__ hg) {
    int i = blockIdx.x * 256 + threadIdx.x;
    if (i < Bz * DM) hg[i] = 0.f;
}

// ---------------------------------------------------------------------------
// Convert weights fp32 -> bf16 (xproj padded from 40 to 64 rows with zeros).
// ---------------------------------------------------------------------------
__global__ __launch_bounds__(256) void k_wconv(const float* __restrict__ inw,
                                               const float* __restrict__ ow,
                                               const float* __restrict__ xw,
                                               bf16_t* __restrict__ inwb,
                                               bf16_t* __restrict__ owb,
                                               bf16_t* __restrict__ xwb) {
    int i = blockIdx.x * 256 + threadIdx.x;
    if (i < DEPTHN * 512 * DM) inwb[i] = f2bf(inw[i]);
    if (i < DEPTHN * DM * DI)  owb[i]  = f2bf(ow[i]);
    if (i < DEPTHN * 64 * DI) {
        int layer = i >> 14, rk = i & 16383, r = rk >> 8, k = rk & 255;
        xwb[i] = (r < NDBL) ? f2bf(xw[((size_t)layer * NDBL + r) * DI + k]) : (bf16_t)0;
    }
}

// ---------------------------------------------------------------------------
__global__ __launch_bounds__(256) void k_inproj(const float* __restrict__ x,
                                                const float* __restrict__ pw,
                                                const float* __restrict__ pb,
                                                float* __restrict__ h) {
    int t = blockIdx.x * 2 + (threadIdx.x >> 7);
    int d = threadIdx.x & 127;
    int b = t >> 13, l = t & (Lz - 1);
    float acc = pb[d];
#pragma unroll
    for (int c = 0; c < 3; ++c)
        acc += x[(size_t)(b * 3 + c) * Lz + l] * pw[d * 3 + c];
    h[(size_t)t * DM + d] = acc;
}

// ---------------------------------------------------------------------------
__global__ __launch_bounds__(256) void k_ln(const float* __restrict__ h,
                                            const float* __restrict__ w,
                                            const float* __restrict__ bias,
                                            bf16_t* __restrict__ xn) {
    int t    = blockIdx.x * 16 + (threadIdx.x >> 4);
    int lane = threadIdx.x & 15;
    const float4* hp = (const float4*)(h + (size_t)t * DM + lane * 8);
    float4 v0 = hp[0], v1 = hp[1];
    float s = v0.x + v0.y + v0.z + v0.w + v1.x + v1.y + v1.z + v1.w;
    float q = v0.x*v0.x + v0.y*v0.y + v0.z*v0.z + v0.w*v0.w +
              v1.x*v1.x + v1.y*v1.y + v1.z*v1.z + v1.w*v1.w;
#pragma unroll
    for (int off = 1; off < 16; off <<= 1) {
        s += __shfl_xor(s, off);
        q += __shfl_xor(q, off);
    }
    float mean = s * (1.f / DM);
    float var  = q * (1.f / DM) - mean * mean;
    float rstd = rsqrtf(var + 1e-5f);
    const float4* wp = (const float4*)(w + lane * 8);
    const float4* bp = (const float4*)(bias + lane * 8);
    float4 w0 = wp[0], w1 = wp[1], b0 = bp[0], b1 = bp[1];
    ushort4 o0, o1;
    o0.x = f2bf((v0.x - mean) * rstd * w0.x + b0.x);
    o0.y = f2bf((v0.y - mean) * rstd * w0.y + b0.y);
    o0.z = f2bf((v0.z - mean) * rstd * w0.z + b0.z);
    o0.w = f2bf((v0.w - mean) * rstd * w0.w + b0.w);
    o1.x = f2bf((v1.x - mean) * rstd * w1.x + b1.x);
    o1.y = f2bf((v1.y - mean) * rstd * w1.y + b1.y);
    o1.z = f2bf((v1.z - mean) * rstd * w1.z + b1.z);
    o1.w = f2bf((v1.w - mean) * rstd * w1.w + b1.w);
    ushort4* op = (ushort4*)(xn + (size_t)t * DM + lane * 8);
    op[0] = o0; op[1] = o1;
}

// ---------------------------------------------------------------------------
// MFMA GEMM 1: [M x 512] = xn[M x 128] @ in_w^T. Block: 64(M) x 256(N).
// ---------------------------------------------------------------------------
#define PADI 264
__global__ __launch_bounds__(256) void k_mfma_in(const bf16_t* __restrict__ A,
                                                 const bf16_t* __restrict__ Wb,
                                                 bf16_t* __restrict__ u_pre,
                                                 bf16_t* __restrict__ z) {
    __shared__ bf16_t tile[64 * PADI];
    int wave = threadIdx.x >> 6, lane = threadIdx.x & 63;
    int lr = lane & 15, lq = lane >> 4;
    int mBase = blockIdx.x * 64;
    int nBase = blockIdx.y * 256;
    int wm = (wave & 1) * 32, wn = (wave >> 1) * 128;
    f4 zf = {0.f, 0.f, 0.f, 0.f};
    f4 acc[2][8];
#pragma unroll
    for (int mi = 0; mi < 2; ++mi)
#pragma unroll
        for (int ni = 0; ni < 8; ++ni) acc[mi][ni] = zf;
    const bf16_t* Ap = A + (size_t)(mBase + wm + lr) * DM + lq * 8;
    const bf16_t* Bp = Wb + (size_t)(nBase + wn + lr) * DM + lq * 8;
#pragma unroll
    for (int kk = 0; kk < DM; kk += 32) {
        bf8 af[2], bq[8];
        af[0] = *(const bf8*)(Ap + kk);
        af[1] = *(const bf8*)(Ap + 16 * DM + kk);
#pragma unroll
        for (int ni = 0; ni < 8; ++ni)
            bq[ni] = *(const bf8*)(Bp + (size_t)ni * 16 * DM + kk);
#pragma unroll
        for (int mi = 0; mi < 2; ++mi)
#pragma unroll
            for (int ni = 0; ni < 8; ++ni)
                acc[mi][ni] = __builtin_amdgcn_mfma_f32_16x16x32_bf16(
                    af[mi], bq[ni], acc[mi][ni], 0, 0, 0);
    }
#pragma unroll
    for (int mi = 0; mi < 2; ++mi)
#pragma unroll
        for (int ni = 0; ni < 8; ++ni)
#pragma unroll
            for (int r = 0; r < 4; ++r)
                tile[(wm + mi * 16 + lq * 4 + r) * PADI + wn + ni * 16 + lr] =
                    f2bf(acc[mi][ni][r]);
    __syncthreads();
    bf16_t* dst = (blockIdx.y == 0) ? u_pre : z;
    for (int i = threadIdx.x; i < 2048; i += 256) {
        int row = i >> 5, col = (i & 31) * 8;
        us8 v = *(const us8*)&tile[row * PADI + col];
        *(us8*)&dst[(size_t)(mBase + row) * DI + col] = v;
    }
}

// ---------------------------------------------------------------------------
// FUSED: conv+SiLU staging -> xproj GEMM (dbl) -> scan1 (P,Q).
// One block per 64-token chunk (== GEMM M-tile == scan chunk).
// LDS: As (post-conv u, 64x264 bf16) + Db (dbl tile, 64x44 f32) = 45 KB.
// ---------------------------------------------------------------------------
#define PADD 44
__global__ __launch_bounds__(256) void k_xp_scan1(
        const bf16_t* __restrict__ u_pre, const bf16_t* __restrict__ xwb,
        const float* __restrict__ cw, const float* __restrict__ cb,
        const float* __restrict__ dtw, const float* __restrict__ dtb,
        const float* __restrict__ Alog,
        float* __restrict__ dbl, float* __restrict__ P, float* __restrict__ Q) {
    __shared__ bf16_t As[64 * PADI];   // 33792 B
    __shared__ float  Db[64 * PADD];   // 11264 B
    int tid = threadIdx.x;
    size_t tokBase = (size_t)blockIdx.x * 64;
    int b  = (int)(tokBase >> 13);
    int p0 = (int)(tokBase & (Lz - 1));
    int c  = p0 >> 6;

    // --- phase A: depthwise conv(k=4)+SiLU from u_pre into As ---
    {
        int d = tid;
        float w0 = cw[d*4+0], w1 = cw[d*4+1], w2 = cw[d*4+2], w3 = cw[d*4+3];
        float bb = cb[d];
        size_t base = tokBase * DI + d;
        float x3 = (p0 >= 3) ? bf2f(u_pre[base - 3*DI]) : 0.f;
        float x2 = (p0 >= 2) ? bf2f(u_pre[base - 2*DI]) : 0.f;
        float x1 = (p0 >= 1) ? bf2f(u_pre[base - 1*DI]) : 0.f;
#pragma unroll 4
        for (int t = 0; t < 64; ++t) {
            float x0 = bf2f(u_pre[base + (size_t)t * DI]);
            float conv = bb + w0*x3 + w1*x2 + w2*x1 + w3*x0;
            float sil = conv * fast_rcp(1.f + __expf(-conv));
            As[t * PADI + d] = f2bf(sil);
            x3 = x2; x2 = x1; x1 = x0;
        }
    }
    __syncthreads();

    // --- phase B: GEMM dbl[64 x 40] = u @ xw^T (N padded to 64) ---
    {
        int wave = tid >> 6, lane = tid & 63;
        int lr = lane & 15, lq = lane >> 4;
        int wm = wave * 16;
        f4 zf = {0.f, 0.f, 0.f, 0.f};
        f4 acc[4];
#pragma unroll
        for (int ni = 0; ni < 4; ++ni) acc[ni] = zf;
        const bf16_t* Bp = xwb + (size_t)lr * DI + lq * 8;
#pragma unroll
        for (int kk = 0; kk < DI; kk += 32) {
            bf8 af = *(const bf8*)&As[(wm + lr) * PADI + lq * 8 + kk];
            bf8 bq[4];
#pragma unroll
            for (int ni = 0; ni < 4; ++ni)
                bq[ni] = *(const bf8*)(Bp + (size_t)ni * 16 * DI + kk);
#pragma unroll
            for (int ni = 0; ni < 4; ++ni)
                acc[ni] = __builtin_amdgcn_mfma_f32_16x16x32_bf16(
                    af, bq[ni], acc[ni], 0, 0, 0);
        }
#pragma unroll
        for (int ni = 0; ni < 4; ++ni)
#pragma unroll
            for (int r = 0; r < 4; ++r) {
                int col = ni * 16 + lr;
                if (col < NDBL)
                    Db[(wm + lq * 4 + r) * PADD + col] = acc[ni][r];
            }
    }
    __syncthreads();
    // dbl -> global (needed by k_scan3_out)
    for (int i = tid; i < 64 * NDBL; i += 256) {
        int row = i / NDBL, col = i - row * NDBL;
        dbl[(tokBase + row) * NDBL + col] = Db[row * PADD + col];
    }

    // --- phase C: scan1 over the chunk (thread = d) ---
    {
        int d = tid;
        float w[DTR];
#pragma unroll
        for (int r = 0; r < DTR; ++r) w[r] = dtw[d * DTR + r];
        float bb = dtb[d];
        float a[DS], q[DS];
#pragma unroll
        for (int s = 0; s < DS; ++s) {
            a[s] = -__expf(Alog[d * DS + s]);
            q[s] = 0.f;
        }
        float a0 = a[0];
        bool fast = true;
#pragma unroll
        for (int s = 1; s < DS; ++s) {
            float ref = a0 * (float)(s + 1);
            fast = fast && (fabsf(a[s] - ref) <= 1e-5f * fabsf(ref) + 1e-7f);
        }
        float sdt = 0.f;
        float p[DS];
#pragma unroll
        for (int s = 0; s < DS; ++s) p[s] = 1.f;

        if (fast) {
#pragma unroll 4
            for (int t = 0; t < CHT; ++t) {
                float4 r0 = *(const float4*)&Db[t * PADD + 0];
                float4 r1 = *(const float4*)&Db[t * PADD + 4];
                float xv = bb + r0.x*w[0] + r0.y*w[1] + r0.z*w[2] + r0.w*w[3]
                              + r1.x*w[4] + r1.y*w[5] + r1.z*w[6] + r1.w*w[7];
                float dtv = (xv > 20.f) ? xv : __logf(1.f + __expf(xv));
                sdt += dtv;
                float uv = bf2f(As[t * PADI + d]);
                float dtu = dtv * uv;
                float e1 = __expf(dtv * a0);
                float bv[DS];
                *(float4*)&bv[0]  = *(const float4*)&Db[t * PADD + 8];
                *(float4*)&bv[4]  = *(const float4*)&Db[t * PADD + 12];
                *(float4*)&bv[8]  = *(const float4*)&Db[t * PADD + 16];
                *(float4*)&bv[12] = *(const float4*)&Db[t * PADD + 20];
                float dA = e1;
#pragma unroll
                for (int s = 0; s < DS; ++s) {
                    q[s] = q[s] * dA + dtu * bv[s];
                    dA *= e1;
                }
            }
#pragma unroll
            for (int s = 0; s < DS; ++s) p[s] = __expf(a[s] * sdt);
        } else {
#pragma unroll 2
            for (int t = 0; t < CHT; ++t) {
                float4 r0 = *(const float4*)&Db[t * PADD + 0];
                float4 r1 = *(const float4*)&Db[t * PADD + 4];
                float xv = bb + r0.x*w[0] + r0.y*w[1] + r0.z*w[2] + r0.w*w[3]
                              + r1.x*w[4] + r1.y*w[5] + r1.z*w[6] + r1.w*w[7];
                float dtv = (xv > 20.f) ? xv : __logf(1.f + __expf(xv));
                float uv = bf2f(As[t * PADI + d]);
                float dtu = dtv * uv;
                float bv[DS];
                *(float4*)&bv[0]  = *(const float4*)&Db[t * PADD + 8];
                *(float4*)&bv[4]  = *(const float4*)&Db[t * PADD + 12];
                *(float4*)&bv[8]  = *(const float4*)&Db[t * PADD + 16];
                *(float4*)&bv[12] = *(const float4*)&Db[t * PADD + 20];
#pragma unroll
                for (int s = 0; s < DS; ++s) {
                    float dA = __expf(dtv * a[s]);
                    p[s] *= dA;
                    q[s] = q[s] * dA + dtu * bv[s];
                }
            }
        }
        size_t o = ((size_t)(b * NCH + c) * DI + d) * DS;
#pragma unroll
        for (int s = 0; s < DS; s += 4) {
            *(float4*)&P[o + s] = make_float4(p[s], p[s+1], p[s+2], p[s+3]);
            *(float4*)&Q[o + s] = make_float4(q[s], q[s+1], q[s+2], q[s+3]);
        }
    }
}

// ---------------------------------------------------------------------------
// Phase 2: scan chunk summaries; P[c] overwritten with entry state.
// ---------------------------------------------------------------------------
__global__ __launch_bounds__(256) void k_scan2(float* __restrict__ P,
                                               const float* __restrict__ Q) {
    int gid = blockIdx.x * 256 + threadIdx.x;
    int b = gid >> 12, r = gid & 4095;            // DI*DS = 4096
    const size_t stride = (size_t)DI * DS;
    size_t base = (size_t)b * NCH * stride + r;
    float hh = 0.f;
    for (int g = 0; g < NCH / 8; ++g) {
        float pp[8], qq[8];
#pragma unroll
        for (int j = 0; j < 8; ++j) {
            size_t o = base + (size_t)(g * 8 + j) * stride;
            pp[j] = P[o]; qq[j] = Q[o];
        }
#pragma unroll
        for (int j = 0; j < 8; ++j) {
            size_t o = base + (size_t)(g * 8 + j) * stride;
            P[o] = hh;
            hh = pp[j] * hh + qq[j];
        }
    }
}

// ---------------------------------------------------------------------------
// FUSED: scan3 (replay with entry state, conv recompute, gating) -> y tile in
// LDS -> out-GEMM h += y @ out_w^T. fp32 epilogue tile aliases the y tile.
// ---------------------------------------------------------------------------
__global__ __launch_bounds__(256) void k_scan3_out(
        const float* __restrict__ dbl, const bf16_t* __restrict__ u_pre,
        const bf16_t* __restrict__ z,
        const float* __restrict__ cw, const float* __restrict__ cb,
        const float* __restrict__ dtw, const float* __restrict__ dtb,
        const float* __restrict__ Alog, const float* __restrict__ Dpv,
        const float* __restrict__ H0, const bf16_t* __restrict__ owb,
        float* __restrict__ h) {
    __shared__ float epit[64 * 132];   // 33792 B; aliased as y tile (bf16)
    __shared__ float Dt8[CHT * 8];
    __shared__ float Bs[CHT * DS];
    __shared__ float Cs[CHT * DS];
    bf16_t* yt = (bf16_t*)epit;        // 64 x PADI bf16, same bytes

    int tid = threadIdx.x;
    size_t tokBase = (size_t)blockIdx.x * 64;
    int b  = (int)(tokBase >> 13);
    int p0 = (int)(tokBase & (Lz - 1));
    int c  = p0 >> 6;

    for (int i = tid; i < CHT * NDBL; i += 256) {
        float v = dbl[tokBase * NDBL + i];
        int t = i / NDBL, col = i - t * NDBL;
        if (col < DTR)            Dt8[t * 8 + col] = v;
        else if (col < DTR + DS)  Bs[t * DS + (col - DTR)] = v;
        else                      Cs[t * DS + (col - DTR - DS)] = v;
    }
    __syncthreads();

    // --- scan phase (thread = d) ---
    {
        int d = tid;
        float cw0 = cw[d*4+0], cw1 = cw[d*4+1], cw2 = cw[d*4+2], cw3 = cw[d*4+3];
        float cbb = cb[d];
        float w[DTR];
#pragma unroll
        for (int r = 0; r < DTR; ++r) w[r] = dtw[d * DTR + r];
        float bb = dtb[d];
        float a[DS], hh[DS];
        size_t ho = ((size_t)(b * NCH + c) * DI + d) * DS;
#pragma unroll
        for (int s = 0; s < DS; ++s) {
            a[s]  = -__expf(Alog[d * DS + s]);
            hh[s] = H0[ho + s];
        }
        float a0 = a[0];
        bool fast = true;
#pragma unroll
        for (int s = 1; s < DS; ++s) {
            float ref = a0 * (float)(s + 1);
            fast = fast && (fabsf(a[s] - ref) <= 1e-5f * fabsf(ref) + 1e-7f);
        }
        float dp = Dpv[d];
        size_t base = tokBase * DI + d;
        const bf16_t* up = u_pre + base;
        const bf16_t* zp = z + base;
        float x3 = (p0 >= 3) ? bf2f(u_pre[base - 3*DI]) : 0.f;
        float x2 = (p0 >= 2) ? bf2f(u_pre[base - 2*DI]) : 0.f;
        float x1 = (p0 >= 1) ? bf2f(u_pre[base - 1*DI]) : 0.f;
        float uc[4], zc[4];
#pragma unroll
        for (int j = 0; j < 4; ++j) {
            uc[j] = bf2f(up[(size_t)j * DI]);
            zc[j] = bf2f(zp[(size_t)j * DI]);
        }
        for (int g = 0; g < CHT / 4; ++g) {
            float un[4] = {0,0,0,0}, zn[4] = {0,0,0,0};
            if (g + 1 < CHT / 4) {
#pragma unroll
                for (int j = 0; j < 4; ++j) {
                    un[j] = bf2f(up[(size_t)((g + 1) * 4 + j) * DI]);
                    zn[j] = bf2f(zp[(size_t)((g + 1) * 4 + j) * DI]);
                }
            }
            if (fast) {
#pragma unroll
                for (int j = 0; j < 4; ++j) {
                    int t = g * 4 + j;
                    float x0 = uc[j];
                    float conv = cbb + cw0*x3 + cw1*x2 + cw2*x1 + cw3*x0;
                    float uv = conv * fast_rcp(1.f + __expf(-conv));
                    x3 = x2; x2 = x1; x1 = x0;
                    float4 r0 = *(const float4*)&Dt8[t * 8];
                    float4 r1 = *(const float4*)&Dt8[t * 8 + 4];
                    float xv = bb + r0.x*w[0] + r0.y*w[1] + r0.z*w[2] + r0.w*w[3]
                                  + r1.x*w[4] + r1.y*w[5] + r1.z*w[6] + r1.w*w[7];
                    float dtv = (xv > 20.f) ? xv : __logf(1.f + __expf(xv));
                    float zv = zc[j];
                    float dtu = dtv * uv;
                    float e1 = __expf(dtv * a0);
                    float bv[DS], cv[DS];
                    *(float4*)&bv[0]  = *(const float4*)&Bs[t * DS + 0];
                    *(float4*)&bv[4]  = *(const float4*)&Bs[t * DS + 4];
                    *(float4*)&bv[8]  = *(const float4*)&Bs[t * DS + 8];
                    *(float4*)&bv[12] = *(const float4*)&Bs[t * DS + 12];
                    *(float4*)&cv[0]  = *(const float4*)&Cs[t * DS + 0];
                    *(float4*)&cv[4]  = *(const float4*)&Cs[t * DS + 4];
                    *(float4*)&cv[8]  = *(const float4*)&Cs[t * DS + 8];
                    *(float4*)&cv[12] = *(const float4*)&Cs[t * DS + 12];
                    float dA = e1;
                    float y = 0.f;
#pragma unroll
                    for (int s = 0; s < DS; ++s) {
                        hh[s] = hh[s] * dA + dtu * bv[s];
                        y += hh[s] * cv[s];
                        dA *= e1;
                    }
                    float sil = zv * fast_rcp(1.f + __expf(-zv));
                    yt[t * PADI + d] = f2bf((y + uv * dp) * sil);
                }
            } else {
#pragma unroll
                for (int j = 0; j < 4; ++j) {
                    int t = g * 4 + j;
                    float x0 = uc[j];
                    float conv = cbb + cw0*x3 + cw1*x2 + cw2*x1 + cw3*x0;
                    float uv = conv * fast_rcp(1.f + __expf(-conv));
                    x3 = x2; x2 = x1; x1 = x0;
                    float4 r0 = *(const float4*)&Dt8[t * 8];
                    float4 r1 = *(const float4*)&Dt8[t * 8 + 4];
                    float xv = bb + r0.x*w[0] + r0.y*w[1] + r0.z*w[2] + r0.w*w[3]
                                  + r1.x*w[4] + r1.y*w[5] + r1.z*w[6] + r1.w*w[7];
                    float dtv = (xv > 20.f) ? xv : __logf(1.f + __expf(xv));
                    float zv = zc[j];
                    float dtu = dtv * uv;
                    float bv[DS], cv[DS];
                    *(float4*)&bv[0]  = *(const float4*)&Bs[t * DS + 0];
                    *(float4*)&bv[4]  = *(const float4*)&Bs[t * DS + 4];
                    *(float4*)&bv[8]  = *(const float4*)&Bs[t * DS + 8];
                    *(float4*)&bv[12] = *(const float4*)&Bs[t * DS + 12];
                    *(float4*)&cv[0]  = *(const float4*)&Cs[t * DS + 0];
                    *(float4*)&cv[4]  = *(const float4*)&Cs[t * DS + 4];
                    *(float4*)&cv[8]  = *(const float4*)&Cs[t * DS + 8];
                    *(float4*)&cv[12] = *(const float4*)&Cs[t * DS + 12];
                    float y = 0.f;
#pragma unroll
                    for (int s = 0; s < DS; ++s) {
                        float dA = __expf(dtv * a[s]);
                        hh[s] = hh[s] * dA + dtu * bv[s];
                        y += hh[s] * cv[s];
                    }
                    float sil = zv * fast_rcp(1.f + __expf(-zv));
                    yt[t * PADI + d] = f2bf((y + uv * dp) * sil);
                }
            }
#pragma unroll
            for (int j = 0; j < 4; ++j) { uc[j] = un[j]; zc[j] = zn[j]; }
        }
    }
    __syncthreads();

    // --- out-GEMM: h[64 x 128] += y[64 x 256] @ out_w^T ---
    int wave = tid >> 6, lane = tid & 63;
    int lr = lane & 15, lq = lane >> 4;
    int wm = wave * 16;
    f4 zf = {0.f, 0.f, 0.f, 0.f};
    f4 acc[8];
#pragma unroll
    for (int ni = 0; ni < 8; ++ni) acc[ni] = zf;
    const bf16_t* Bp = owb + (size_t)lr * DI + lq * 8;
#pragma unroll
    for (int kk = 0; kk < DI; kk += 32) {
        bf8 af = *(const bf8*)&yt[(wm + lr) * PADI + lq * 8 + kk];
        bf8 bq[8];
#pragma unroll
        for (int ni = 0; ni < 8; ++ni)
            bq[ni] = *(const bf8*)(Bp + (size_t)ni * 16 * DI + kk);
#pragma unroll
        for (int ni = 0; ni < 8; ++ni)
            acc[ni] = __builtin_amdgcn_mfma_f32_16x16x32_bf16(
                af, bq[ni], acc[ni], 0, 0, 0);
    }
    __syncthreads();   // all y reads done; epit may be overwritten
#pragma unroll
    for (int ni = 0; ni < 8; ++ni)
#pragma unroll
        for (int r = 0; r < 4; ++r)
            epit[(wm + lq * 4 + r) * 132 + ni * 16 + lr] = acc[ni][r];
    __syncthreads();
    for (int i = tid; i < 2048; i += 256) {
        int row = i >> 5, col = (i & 31) * 4;
        float4 v = *(const float4*)&epit[row * 132 + col];
        float4 old = *(const float4*)&h[(tokBase + row) * DM + col];
        old.x += v.x; old.y += v.y; old.z += v.z; old.w += v.w;
        *(float4*)&h[(tokBase + row) * DM + col] = old;
    }
}

// ---------------------------------------------------------------------------
__global__ __launch_bounds__(256) void k_final(float* __restrict__ h,
                                               const float* __restrict__ w,
                                               const float* __restrict__ bias,
                                               float* __restrict__ hg) {
    __shared__ float sbuf[DM];
    int t    = blockIdx.x * 16 + (threadIdx.x >> 4);
    int lane = threadIdx.x & 15;
    int b    = t >> 13;
    if (threadIdx.x < DM) sbuf[threadIdx.x] = 0.f;
    __syncthreads();
    float4* hp = (float4*)(h + (size_t)t * DM + lane * 8);
    float4 v0 = hp[0], v1 = hp[1];
    float s = v0.x + v0.y + v0.z + v0.w + v1.x + v1.y + v1.z + v1.w;
    float q = v0.x*v0.x + v0.y*v0.y + v0.z*v0.z + v0.w*v0.w +
              v1.x*v1.x + v1.y*v1.y + v1.z*v1.z + v1.w*v1.w;
#pragma unroll
    for (int off = 1; off < 16; off <<= 1) {
        s += __shfl_xor(s, off);
        q += __shfl_xor(q, off);
    }
    float mean = s * (1.f / DM);
    float var  = q * (1.f / DM) - mean * mean;
    float rstd = rsqrtf(var + 1e-5f);
    const float4* wp = (const float4*)(w + lane * 8);
    const float4* bp = (const float4*)(bias + lane * 8);
    float4 w0 = wp[0], w1 = wp[1], b0 = bp[0], b1 = bp[1];
    float4 o0, o1;
    o0.x = (v0.x - mean) * rstd * w0.x + b0.x;
    o0.y = (v0.y - mean) * rstd * w0.y + b0.y;
    o0.z = (v0.z - mean) * rstd * w0.z + b0.z;
    o0.w = (v0.w - mean) * rstd * w0.w + b0.w;
    o1.x = (v1.x - mean) * rstd * w1.x + b1.x;
    o1.y = (v1.y - mean) * rstd * w1.y + b1.y;
    o1.z = (v1.z - mean) * rstd * w1.z + b1.z;
    o1.w = (v1.w - mean) * rstd * w1.w + b1.w;
    hp[0] = o0; hp[1] = o1;
    int dbase = lane * 8;
    atomicAdd(&sbuf[dbase + 0], o0.x); atomicAdd(&sbuf[dbase + 1], o0.y);
    atomicAdd(&sbuf[dbase + 2], o0.z); atomicAdd(&sbuf[dbase + 3], o0.w);
    atomicAdd(&sbuf[dbase + 4], o1.x); atomicAdd(&sbuf[dbase + 5], o1.y);
    atomicAdd(&sbuf[dbase + 6], o1.z); atomicAdd(&sbuf[dbase + 7], o1.w);
    __syncthreads();
    if (threadIdx.x < DM)
        atomicAdd(&hg[b * DM + threadIdx.x], sbuf[threadIdx.x] * (1.f / Lz));
}

// ---------------------------------------------------------------------------
extern "C" void kernel_launch(void* const* d_in, const int* in_sizes, int n_in,
                              void* d_out, int out_size, void* d_ws, size_t ws_size,
                              hipStream_t stream) {
    const float* x       = (const float*)d_in[0];
    const float* proj_w  = (const float*)d_in[1];
    const float* proj_b  = (const float*)d_in[2];
    const float* ln_w    = (const float*)d_in[3];
    const float* ln_b    = (const float*)d_in[4];
    const float* in_w    = (const float*)d_in[5];
    const float* conv_w  = (const float*)d_in[6];
    const float* conv_b  = (const float*)d_in[7];
    const float* xproj_w = (const float*)d_in[8];
    const float* dt_w    = (const float*)d_in[9];
    const float* dt_b    = (const float*)d_in[10];
    const float* A_log   = (const float*)d_in[11];
    const float* Dp      = (const float*)d_in[12];
    const float* out_w   = (const float*)d_in[13];
    const float* lnout_w = (const float*)d_in[14];
    const float* lnout_b = (const float*)d_in[15];

    float* out = (float*)d_out;
    float* h   = out;                        // [BL][128] lives in d_out
    float* hg  = out + (size_t)BLz * DM;     // [B][128]

    // Workspace layout (~107 MiB). Q aliases xn (dead after k_mfma_in).
    char* ws = (char*)d_ws;
    bf16_t* xn    = (bf16_t*)(ws);                                    // 16 MiB
    bf16_t* u_pre = (bf16_t*)(ws + 16777216ULL);                      // 32 MiB
    bf16_t* z     = (bf16_t*)(ws + 50331648ULL);                      // 32 MiB
    float*  dbl   = (float*) (ws + 83886080ULL);                      // 10 MiB
    float*  P     = (float*) (ws + 94371840ULL);                      // 16 MiB
    bf16_t* inwb  = (bf16_t*)(ws + 111149056ULL);                     // 512 KiB
    bf16_t* owb   = (bf16_t*)(ws + 111673344ULL);                     // 256 KiB
    bf16_t* xwb   = (bf16_t*)(ws + 111935488ULL);                     // 128 KiB
    float*  Q     = (float*)xn;

    k_zero_hg<<<4, 256, 0, stream>>>(hg);
    k_wconv<<<1024, 256, 0, stream>>>(in_w, out_w, xproj_w, inwb, owb, xwb);
    k_inproj<<<BLz / 2, 256, 0, stream>>>(x, proj_w, proj_b, h);

    for (int i = 0; i < DEPTHN; ++i) {
        k_ln<<<BLz / 16, 256, 0, stream>>>(h, ln_w + i * DM, ln_b + i * DM, xn);
        k_mfma_in<<<dim3(BLz / 64, 2), 256, 0, stream>>>(
            xn, inwb + (size_t)i * 512 * DM, u_pre, z);
        k_xp_scan1<<<BLz / 64, 256, 0, stream>>>(
            u_pre, xwb + (size_t)i * 64 * DI,
            conv_w + i * DI * 4, conv_b + i * DI,
            dt_w + i * DI * DTR, dt_b + i * DI, A_log + i * DI * DS,
            dbl, P, Q);
        k_scan2<<<(Bz * DI * DS) / 256, 256, 0, stream>>>(P, Q);
        k_scan3_out<<<BLz / 64, 256, 0, stream>>>(
            dbl, u_pre, z,
            conv_w + i * DI * 4, conv_b + i * DI,
            dt_w + i * DI * DTR, dt_b + i * DI,
            A_log + i * DI * DS, Dp + i * DI, P,
            owb + (size_t)i * DM * DI, h);
    }

    k_final<<<BLz / 16, 256, 0, stream>>>(h, lnout_w, lnout_b, hg);
}